// Round 8
// baseline (245.543 us; speedup 1.0000x reference)
//
#include <hip/hip_runtime.h>

#define SEQ 4096
#define DIM 1280
#define NH 16
#define HD 80
#define HQ 96
#define TDIM 3840

// softmax scale (1/sqrt(80)) * log2(e), folded into Q at repack
#define QSC 0.16129842980505168f

typedef __bf16 bf16x8 __attribute__((ext_vector_type(8)));
typedef __bf16 bf16x4 __attribute__((ext_vector_type(4)));
typedef float f32x4 __attribute__((ext_vector_type(4)));

__device__ __forceinline__ unsigned short f2bf(float f) {
  unsigned int u = __builtin_bit_cast(unsigned int, f);
  u += 0x7FFF + ((u >> 16) & 1);
  return (unsigned short)(u >> 16);
}
__device__ __forceinline__ float bf2f(unsigned short b) {
  unsigned int u = ((unsigned int)b) << 16;
  return __builtin_bit_cast(float, u);
}
__device__ __forceinline__ unsigned int cvtpk(float a, float b) {
  unsigned int r;
  asm("v_cvt_pk_bf16_f32 %0, %1, %2" : "=v"(r) : "v"(a), "v"(b));
  return r;
}

__device__ __forceinline__ void gload_lds16(const void* g, void* l) {
  __builtin_amdgcn_global_load_lds(
      (const __attribute__((address_space(1))) unsigned int*)g,
      (__attribute__((address_space(3))) unsigned int*)l, 16, 0, 0);
}

// ---------------- fused prep: fp32->bf16 x3 + cos/sin table ----------------
__global__ __launch_bounds__(256) void prep(const float* __restrict__ X,
                                            const float* __restrict__ Wq,
                                            const float* __restrict__ Wp,
                                            const float* __restrict__ rope,
                                            unsigned short* __restrict__ Xb,
                                            unsigned short* __restrict__ Wqb,
                                            unsigned short* __restrict__ Wpb,
                                            float* __restrict__ ct, float* __restrict__ st) {
  constexpr int N0 = SEQ * DIM / 4;
  constexpr int N1 = TDIM * DIM / 4;
  constexpr int N2 = DIM * DIM / 4;
  constexpr int N3 = SEQ * HD / 4;
  const int stride = gridDim.x * 256;
  for (int i = blockIdx.x * 256 + threadIdx.x; i < N0 + N1 + N2 + N3; i += stride) {
    if (i < N0 + N1 + N2) {
      const float4* src;
      unsigned short* dst;
      int j;
      if (i < N0) {
        src = (const float4*)X; dst = Xb; j = i;
      } else if (i < N0 + N1) {
        src = (const float4*)Wq; dst = Wqb; j = i - N0;
      } else {
        src = (const float4*)Wp; dst = Wpb; j = i - N0 - N1;
      }
      float4 f = src[j];
      ushort4 o;
      o.x = f2bf(f.x); o.y = f2bf(f.y); o.z = f2bf(f.z); o.w = f2bf(f.w);
      ((ushort4*)dst)[j] = o;
    } else {
      const int j = i - N0 - N1 - N2;
      float4 v = ((const float4*)rope)[j];
      float4 c, s;
      c.x = cosf(v.x); c.y = cosf(v.y); c.z = cosf(v.z); c.w = cosf(v.w);
      s.x = sinf(v.x); s.y = sinf(v.y); s.z = sinf(v.z); s.w = sinf(v.w);
      ((float4*)ct)[j] = c;
      ((float4*)st)[j] = s;
    }
  }
}

// ---------------- GEMM 256x256: C = A(MxK) @ B(NxK)^T + bias, bf16 out ----------------
// 8 waves (2M x 4N), BK=32, per-wave 128x64 out (32 MFMA/step). LDS chunk-major
// [4 ci][256 row][16B] per matrix (conflict-free reads, linear gload_lds dest).
// Ring-2 + counted vmcnt(4) (R7-proven sync skeleton). Grid 1-D with XCD swizzle.
__global__ __launch_bounds__(512, 1) void gemm256(const unsigned short* __restrict__ A,
                                                  const unsigned short* __restrict__ B,
                                                  const float* __restrict__ bias,
                                                  unsigned short* __restrict__ Cout,
                                                  int N, int K, int ntn) {
  __shared__ char smem[65536];  // A: 2 x 16KB at 0; B: 2 x 16KB at 32768
  const int tid = threadIdx.x;
  const int l = tid & 63, w = tid >> 6;
  const int row16 = l & 15, kg = l >> 4;
  const int wr = w >> 2, wc = w & 3;

  // XCD-swizzled block -> tile coords (grid % 8 == 0 required)
  const int nwg = gridDim.x;
  const int cpx = nwg >> 3;
  const int swz = (blockIdx.x & 7) * cpx + (blockIdx.x >> 3);
  const int ny = swz / ntn, nx = swz - ny * ntn;
  const int brow = ny * 256, bcol = nx * 256;

  const size_t Kb = (size_t)K * 2;  // row stride bytes
  const char* Ag = (const char*)A + (size_t)brow * Kb;
  const char* Bg = (const char*)B + (size_t)bcol * Kb;

  // staging: 4 units/thread (2 A + 2 B); unit u = tid + 512*j
  unsigned soffA[2], soffB[2], sdstA[2], sdstB[2];
#pragma unroll
  for (int j = 0; j < 2; ++j) {
    const int u = tid + 512 * j;           // 0..1023
    soffA[j] = (unsigned)((u & 255) * Kb) + (u >> 8) * 16;
    sdstA[j] = u * 16;
    soffB[j] = soffA[j];
    sdstB[j] = 32768 + u * 16;
  }
  auto SG = [&](int kt, int b) {
    const char* a = Ag + kt * 64;
    const char* bp = Bg + kt * 64;
#pragma unroll
    for (int j = 0; j < 2; ++j) gload_lds16(a + soffA[j], smem + b * 16384 + sdstA[j]);
#pragma unroll
    for (int j = 0; j < 2; ++j) gload_lds16(bp + soffB[j], smem + b * 16384 + sdstB[j]);
  };

  f32x4 acc[8][4] = {};
  // LDS read bases: af[mi]: kg*4096 + (wr*128+mi*16+row16)*16 ; bf[ni]: +32768, wc*64 rows
  const int abase = kg * 4096 + (wr * 128 + row16) * 16;
  const int bbase = 32768 + kg * 4096 + (wc * 64 + row16) * 16;

  auto COMP = [&](int b) {
    const char* Ab = smem + b * 16384;
    bf16x8 bf[4];
#pragma unroll
    for (int ni = 0; ni < 4; ++ni) bf[ni] = *(const bf16x8*)(Ab + bbase + ni * 256);
    bf16x8 af[8];
#pragma unroll
    for (int mi = 0; mi < 8; ++mi) af[mi] = *(const bf16x8*)(Ab + abase + mi * 256);
    __builtin_amdgcn_s_setprio(1);
#pragma unroll
    for (int mi = 0; mi < 8; ++mi)
#pragma unroll
      for (int ni = 0; ni < 4; ++ni)
        acc[mi][ni] = __builtin_amdgcn_mfma_f32_16x16x32_bf16(af[mi], bf[ni], acc[mi][ni], 0, 0, 0);
    __builtin_amdgcn_s_setprio(0);
  };

  const int nk = K >> 5;
  SG(0, 0);
#pragma unroll 1
  for (int kt = 0; kt < nk - 1; ++kt) {
    SG(kt + 1, (kt + 1) & 1);
    asm volatile("s_waitcnt vmcnt(4)" ::: "memory");
    __builtin_amdgcn_s_barrier();
    __builtin_amdgcn_sched_barrier(0);
    COMP(kt & 1);
    asm volatile("" ::: "memory");
    __builtin_amdgcn_s_barrier();
  }
  asm volatile("s_waitcnt vmcnt(0)" ::: "memory");
  __builtin_amdgcn_s_barrier();
  __builtin_amdgcn_sched_barrier(0);
  COMP((nk - 1) & 1);

#pragma unroll
  for (int ni = 0; ni < 4; ++ni) {
    const int col = bcol + wc * 64 + ni * 16 + row16;
    const float bv = bias[col];
#pragma unroll
    for (int mi = 0; mi < 8; ++mi) {
      const int row = brow + wr * 128 + mi * 16 + kg * 4;
#pragma unroll
      for (int r = 0; r < 4; ++r)
        Cout[(size_t)(row + r) * N + col] = f2bf(acc[mi][ni][r] + bv);
    }
  }
}

// ---------------- GEMM: C = A(MxK) @ B(NxK)^T + bias (128^2, ring-2) ----------------
template <int F32OUT>
__global__ __launch_bounds__(256) void gemm_bt(const unsigned short* __restrict__ A,
                                               const unsigned short* __restrict__ B,
                                               const float* __restrict__ bias,
                                               void* __restrict__ Cout, int M, int N, int K) {
  __shared__ unsigned short As[2][4096];
  __shared__ unsigned short Bs[2][4096];
  const int t = threadIdx.x;
  const int l = t & 63, w = t >> 6;
  const int row16 = l & 15, kg = l >> 4;
  const int brow = blockIdx.y * 128, bcol = blockIdx.x * 128;
  const int wr = w >> 1, wc = w & 1;
  f32x4 acc[4][4] = {};
  const size_t Ks = (size_t)K;
  const unsigned short* Ag = A + (brow + (t >> 2)) * Ks + (t & 3) * 8;
  const unsigned short* Bg = B + (bcol + (t >> 2)) * Ks + (t & 3) * 8;
  const int woff = w * 512;
  const int nk = K >> 5;

  auto SG = [&](int kt, int b) {
    const unsigned short* a = Ag + kt * 32;
    const unsigned short* bp = Bg + kt * 32;
    gload_lds16(a, &As[b][woff]);
    gload_lds16(a + 64 * Ks, &As[b][woff + 2048]);
    gload_lds16(bp, &Bs[b][woff]);
    gload_lds16(bp + 64 * Ks, &Bs[b][woff + 2048]);
  };
  auto COMP = [&](int b) {
    bf16x8 af[4], bfr[4];
#pragma unroll
    for (int m = 0; m < 4; ++m)
      af[m] = *(const bf16x8*)&As[b][(wr * 64 + m * 16 + row16) * 32 + kg * 8];
#pragma unroll
    for (int n = 0; n < 4; ++n)
      bfr[n] = *(const bf16x8*)&Bs[b][(wc * 64 + n * 16 + row16) * 32 + kg * 8];
#pragma unroll
    for (int m = 0; m < 4; ++m)
#pragma unroll
      for (int n = 0; n < 4; ++n)
        acc[m][n] = __builtin_amdgcn_mfma_f32_16x16x32_bf16(af[m], bfr[n], acc[m][n], 0, 0, 0);
  };

  SG(0, 0);
#pragma unroll 1
  for (int kt = 0; kt < nk - 1; ++kt) {
    SG(kt + 1, (kt + 1) & 1);
    asm volatile("s_waitcnt vmcnt(4)" ::: "memory");
    __builtin_amdgcn_s_barrier();
    __builtin_amdgcn_sched_barrier(0);
    COMP(kt & 1);
    asm volatile("" ::: "memory");
    __builtin_amdgcn_s_barrier();
  }
  asm volatile("s_waitcnt vmcnt(0)" ::: "memory");
  __builtin_amdgcn_s_barrier();
  __builtin_amdgcn_sched_barrier(0);
  COMP((nk - 1) & 1);

#pragma unroll
  for (int n = 0; n < 4; ++n) {
    const int col = bcol + wc * 64 + n * 16 + row16;
    const float bv = bias[col];
#pragma unroll
    for (int m = 0; m < 4; ++m) {
      const int row = brow + wr * 64 + m * 16 + kg * 4;
#pragma unroll
      for (int r = 0; r < 4; ++r) {
        float v = acc[m][n][r] + bv;
        if (F32OUT)
          ((float*)Cout)[(size_t)(row + r) * N + col] = v;
        else
          ((unsigned short*)Cout)[(size_t)(row + r) * N + col] = f2bf(v);
      }
    }
  }
}

// ---------------- RoPE + repack Q,K -> [h][s][96]; Q pre-scaled ----------------
__global__ __launch_bounds__(256) void rope_qk2(const unsigned short* __restrict__ Y,
                                                const float* __restrict__ ct,
                                                const float* __restrict__ st,
                                                unsigned short* __restrict__ Qr,
                                                unsigned short* __restrict__ Kr) {
  const int s = blockIdx.x, tid = threadIdx.x;
  const unsigned short* yq = Y + (size_t)s * TDIM;
  const unsigned short* yk = yq + DIM;
  for (int i = tid; i < 640; i += 256) {
    const int h = i / 40, j = i - h * 40;
    const float c0 = ct[s * HD + j], c1 = ct[s * HD + j + 40];
    const float s0 = st[s * HD + j], s1 = st[s * HD + j + 40];
    const float q0 = bf2f(yq[h * HD + j]), q1 = bf2f(yq[h * HD + j + 40]);
    const float k0 = bf2f(yk[h * HD + j]), k1 = bf2f(yk[h * HD + j + 40]);
    const size_t o = ((size_t)h * SEQ + s) * HQ;
    Qr[o + j] = f2bf((q0 * c0 - q1 * s0) * QSC);
    Qr[o + j + 40] = f2bf((q1 * c1 + q0 * s1) * QSC);
    Kr[o + j] = f2bf(k0 * c0 - k1 * s0);
    Kr[o + j + 40] = f2bf(k1 * c1 + k0 * s1);
  }
  {  // zero pad d = 80..95 for all 16 heads
    const int h = tid >> 4, dp = 80 + (tid & 15);
    const size_t o = ((size_t)h * SEQ + s) * HQ + dp;
    Qr[o] = 0;
    Kr[o] = 0;
  }
}

// ---------------- V transpose -> permuted image Vp[h][d][4096] ----------------
__global__ __launch_bounds__(256) void vtrans3(const unsigned short* __restrict__ Y,
                                               unsigned short* __restrict__ Vp) {
  __shared__ unsigned short tile[64][128];
  const int h = blockIdx.x, s0 = blockIdx.y * 64, tid = threadIdx.x;
  const unsigned short* src = Y + 2 * DIM + h * HD;
  for (int u = tid; u < 640; u += 256) {
    const int s = u / 10, j = u - s * 10;
    uint4 v = *(const uint4*)(src + (size_t)(s0 + s) * TDIM + j * 8);
    *(uint4*)&tile[s][(j ^ ((s >> 3) & 7)) << 3] = v;
  }
  __syncthreads();
  for (int u = tid; u < 640; u += 256) {
    const int d = u >> 3, g = u & 7;
    const int gl = g ^ (d & 7);
    const int base_s = (gl & 1) * 32 + (gl >> 1) * 4;
    unsigned short tmp[8];
#pragma unroll
    for (int sub = 0; sub < 8; ++sub) {
      const int s = base_s + (sub >> 2) * 16 + (sub & 3);
      tmp[sub] = tile[s][(((d >> 3) ^ ((s >> 3) & 7)) << 3) + (d & 7)];
    }
    *(uint4*)(Vp + (size_t)(h * HD + d) * SEQ + s0 + g * 8) = *(uint4*)tmp;
  }
}

// ---------------- Flash attention v7: ring-3 counted vmcnt + fast-path softmax ----
__global__ __launch_bounds__(256, 2) void attn7(const unsigned short* __restrict__ Qr,
                                                const unsigned short* __restrict__ Kr,
                                                const unsigned short* __restrict__ Vp,
                                                unsigned short* __restrict__ Ob) {
  constexpr int KBYT = 12288;
  constexpr int VBYT = 10240;
  constexpr int BUFB = KBYT + VBYT;  // 22528
  constexpr int NT = SEQ / 64;       // 64 tiles
  __shared__ char smem[3 * BUFB];

  const int tid = threadIdx.x;
  const int l = tid & 63, w = tid >> 6;
  const int row16 = l & 15, kg = l >> 4;
  const int bid = blockIdx.x;
  const int h = bid & 15;
  const int q0 = (bid >> 4) * 128 + w * 32;
  const size_t hs = (size_t)h * SEQ;
  const bool loww = (w < 2);

  const unsigned short* Qh = Qr + hs * HQ;
  const char* Kh = (const char*)(Kr + hs * HQ);
  const char* Vh = (const char*)(Vp + (size_t)h * HD * SEQ);

  // staging: 1408 16B-units (768 K + 640 V); unit u = tid + 256*i
  unsigned soff[6], sdst[6];
  bool isk[6];
  const int cnt = (tid < 128) ? 6 : 5;
#pragma unroll
  for (int i = 0; i < 6; ++i) {
    const int u = tid + 256 * i;
    if (u < 768) {
      soff[i] = (u & 63) * 192 + (u >> 6) * 16;
      isk[i] = true;
    } else {
      const int v = u - 768;
      soff[i] = (v >> 3) * 8192 + (v & 7) * 16;
      isk[i] = false;
    }
    sdst[i] = u << 4;
  }
  auto STAGE = [&](int t, int bb) {
    const char* kb = Kh + (size_t)t * 12288;
    const char* vb = Vh + (size_t)t * 128;
#pragma unroll
    for (int i = 0; i < 6; ++i)
      if (i < cnt) gload_lds16((isk[i] ? kb : vb) + soff[i], smem + bb + sdst[i]);
  };

  // LDS read bases (tile-invariant)
  const int kbase = row16 * 16;  // + (4c+kg)*1024 + nb*256
  int vb_[2];
#pragma unroll
  for (int ks = 0; ks < 2; ++ks)
    vb_[ks] = KBYT + row16 * 128 + ((((kg << 1) | ks) ^ (row16 & 7)) << 4);  // + n5*2048

  // Q fragments (B-operand of swapped QK^T): q = q0 + qb*16 + row16
  bf16x8 qf[2][3];
#pragma unroll
  for (int qb = 0; qb < 2; ++qb)
#pragma unroll
    for (int c = 0; c < 3; ++c)
      qf[qb][c] = *(const bf16x8*)&Qh[(size_t)(q0 + qb * 16 + row16) * HQ + c * 32 + kg * 8];
  // Force the compiler's vmcnt wait for qf HERE (pre-pipeline), not inside the loop.
  asm volatile("" ::"v"(qf[0][0]), "v"(qf[0][1]), "v"(qf[0][2]));
  asm volatile("" ::"v"(qf[1][0]), "v"(qf[1][1]), "v"(qf[1][2]));

  union { bf16x8 v; unsigned int u[4]; } ones;
  ones.u[0] = ones.u[1] = ones.u[2] = ones.u[3] = 0x3F803F80u;

  float m_run[2] = {-3.0e38f, -3.0e38f};
  f32x4 oacc[2][6] = {};  // [qb][d-block 0..4, 5 = row-sum l]

  auto COMPUTE = [&](const char* B) {
    // ---- QK^T: per d-chunk c, load 4 K-frags then 8 MFMAs ----
    f32x4 sacc[2][4] = {};
#pragma unroll
    for (int c = 0; c < 3; ++c) {
      bf16x8 kf[4];
      const char* kc = B + (4 * c + kg) * 1024 + kbase;
#pragma unroll
      for (int nb = 0; nb < 4; ++nb) kf[nb] = *(const bf16x8*)(kc + nb * 256);
      __builtin_amdgcn_s_setprio(1);
#pragma unroll
      for (int qb = 0; qb < 2; ++qb)
#pragma unroll
        for (int nb = 0; nb < 4; ++nb)
          sacc[qb][nb] =
              __builtin_amdgcn_mfma_f32_16x16x32_bf16(kf[nb], qf[qb][c], sacc[qb][nb], 0, 0, 0);
      __builtin_amdgcn_s_setprio(0);
    }
    // ---- V fragments (one b128 per (n5, ks)) ----
    bf16x8 vf[5][2];
#pragma unroll
    for (int n5 = 0; n5 < 5; ++n5)
#pragma unroll
      for (int ks = 0; ks < 2; ++ks) vf[n5][ks] = *(const bf16x8*)(B + vb_[ks] + n5 * 2048);
    // ---- softmax: per-lane local max; cross-lane ONLY when threshold exceeded ----
    float pl[2];
#pragma unroll
    for (int qb = 0; qb < 2; ++qb) {
      float a0 = fmaxf(fmaxf(sacc[qb][0][0], sacc[qb][0][1]), fmaxf(sacc[qb][0][2], sacc[qb][0][3]));
      float a1 = fmaxf(fmaxf(sacc[qb][1][0], sacc[qb][1][1]), fmaxf(sacc[qb][1][2], sacc[qb][1][3]));
      float a2 = fmaxf(fmaxf(sacc[qb][2][0], sacc[qb][2][1]), fmaxf(sacc[qb][2][2], sacc[qb][2][3]));
      float a3 = fmaxf(fmaxf(sacc[qb][3][0], sacc[qb][3][1]), fmaxf(sacc[qb][3][2], sacc[qb][3][3]));
      pl[qb] = fmaxf(fmaxf(a0, a1), fmaxf(a2, a3));
    }
    // fast path: no lane's local max grew past m_run + 8 -> keep m_run, P <= 2^8
    if (!__all((pl[0] - m_run[0] <= 8.0f) & (pl[1] - m_run[1] <= 8.0f))) {
#pragma unroll
      for (int qb = 0; qb < 2; ++qb) {
        float m0 = pl[qb];
        m0 = fmaxf(m0, __shfl_xor(m0, 16, 64));
        m0 = fmaxf(m0, __shfl_xor(m0, 32, 64));
        const float mn = fmaxf(m_run[qb], m0);
        const float fac = __builtin_amdgcn_exp2f(m_run[qb] - mn);
        m_run[qb] = mn;
#pragma unroll
        for (int n6 = 0; n6 < 6; ++n6)
#pragma unroll
          for (int r = 0; r < 4; ++r) oacc[qb][n6][r] *= fac;
      }
    }
#pragma unroll
    for (int qb = 0; qb < 2; ++qb)
#pragma unroll
      for (int nb = 0; nb < 4; ++nb)
#pragma unroll
        for (int r = 0; r < 4; ++r)
          sacc[qb][nb][r] = __builtin_amdgcn_exp2f(sacc[qb][nb][r] - m_run[qb]);
    // ---- pack P -> bf16 (k-map matches Vp image) and PV + row-sum ----
    __builtin_amdgcn_s_setprio(1);
#pragma unroll
    for (int qb = 0; qb < 2; ++qb)
#pragma unroll
      for (int ks = 0; ks < 2; ++ks) {
        union { bf16x8 v; unsigned int u[4]; } pf;
        pf.u[0] = cvtpk(sacc[qb][2 * ks][0], sacc[qb][2 * ks][1]);
        pf.u[1] = cvtpk(sacc[qb][2 * ks][2], sacc[qb][2 * ks][3]);
        pf.u[2] = cvtpk(sacc[qb][2 * ks + 1][0], sacc[qb][2 * ks + 1][1]);
        pf.u[3] = cvtpk(sacc[qb][2 * ks + 1][2], sacc[qb][2 * ks + 1][3]);
#pragma unroll
        for (int n5 = 0; n5 < 5; ++n5)
          oacc[qb][n5] =
              __builtin_amdgcn_mfma_f32_16x16x32_bf16(vf[n5][ks], pf.v, oacc[qb][n5], 0, 0, 0);
        oacc[qb][5] = __builtin_amdgcn_mfma_f32_16x16x32_bf16(ones.v, pf.v, oacc[qb][5], 0, 0, 0);
      }
    __builtin_amdgcn_s_setprio(0);
  };

  // ---- prologue: fill stages for tiles 0 and 1 ----
  STAGE(0, 0);
  STAGE(1, BUFB);

  int cur = 0;
#pragma unroll 1
  for (int t = 0; t < NT - 2; ++t) {
    const int sb = (cur == 0) ? 2 : (cur - 1);  // (t+2)%3
    STAGE(t + 2, sb * BUFB);
    if (loww)
      asm volatile("s_waitcnt vmcnt(12)" ::: "memory");
    else
      asm volatile("s_waitcnt vmcnt(10)" ::: "memory");
    __builtin_amdgcn_s_barrier();
    __builtin_amdgcn_sched_barrier(0);
    COMPUTE(smem + cur * BUFB);
    asm volatile("" ::: "memory");
    __builtin_amdgcn_s_barrier();
    cur = (cur == 2) ? 0 : (cur + 1);
  }
  if (loww)
    asm volatile("s_waitcnt vmcnt(6)" ::: "memory");
  else
    asm volatile("s_waitcnt vmcnt(5)" ::: "memory");
  __builtin_amdgcn_s_barrier();
  __builtin_amdgcn_sched_barrier(0);
  COMPUTE(smem + cur * BUFB);
  asm volatile("" ::: "memory");
  __builtin_amdgcn_s_barrier();
  cur = (cur == 2) ? 0 : (cur + 1);
  asm volatile("s_waitcnt vmcnt(0)" ::: "memory");
  __builtin_amdgcn_s_barrier();
  __builtin_amdgcn_sched_barrier(0);
  COMPUTE(smem + cur * BUFB);

  // ---- epilogue: d = n5*16 + kg*4 + r, q = q0 + qb*16 + row16 ----
#pragma unroll
  for (int qb = 0; qb < 2; ++qb) {
    const float rl = 1.0f / oacc[qb][5][0];
    unsigned short* orow = Ob + (size_t)(q0 + qb * 16 + row16) * DIM + h * HD + kg * 4;
#pragma unroll
    for (int n5 = 0; n5 < 5; ++n5) {
      ushort4 o;
      o.x = f2bf(oacc[qb][n5][0] * rl);
      o.y = f2bf(oacc[qb][n5][1] * rl);
      o.z = f2bf(oacc[qb][n5][2] * rl);
      o.w = f2bf(oacc[qb][n5][3] * rl);
      *(ushort4*)(orow + n5 * 16) = o;
    }
  }
}

// ---------------- host ----------------
extern "C" void kernel_launch(void* const* d_in, const int* in_sizes, int n_in, void* d_out,
                              int out_size, void* d_ws, size_t ws_size, hipStream_t stream) {
  (void)in_sizes; (void)n_in; (void)out_size; (void)ws_size;
  const float* hidden = (const float*)d_in[0];
  const float* rope = (const float*)d_in[2];
  const float* qkv_w = (const float*)d_in[3];
  const float* qkv_b = (const float*)d_in[4];
  const float* proj_w = (const float*)d_in[5];
  const float* proj_b = (const float*)d_in[6];

  char* p = (char*)d_ws;
  unsigned short* Xb = (unsigned short*)p;       p += (size_t)SEQ * DIM * 2;
  unsigned short* Wq = (unsigned short*)p;       p += (size_t)TDIM * DIM * 2;
  unsigned short* Wp = (unsigned short*)p;       p += (size_t)DIM * DIM * 2;
  float* ct = (float*)p;                         p += (size_t)SEQ * HD * 4;
  float* st = (float*)p;                         p += (size_t)SEQ * HD * 4;
  unsigned short* Y = (unsigned short*)p;        p += (size_t)SEQ * TDIM * 2;
  unsigned short* Qr = (unsigned short*)p;       p += (size_t)NH * SEQ * HQ * 2;
  unsigned short* Kr = (unsigned short*)p;       p += (size_t)NH * SEQ * HQ * 2;
  unsigned short* Vp = (unsigned short*)p;       p += (size_t)NH * HD * SEQ * 2;
  unsigned short* Ob = (unsigned short*)p;       p += (size_t)SEQ * DIM * 2;

  prep<<<2048, 256, 0, stream>>>(hidden, qkv_w, proj_w, rope, Xb, Wq, Wp, ct, st);
  // QKV GEMM: 256^2 tile, grid 16x15 = 240 (240 % 8 == 0 for XCD swizzle)
  gemm256<<<(SEQ / 256) * (TDIM / 256), 512, 0, stream>>>(Xb, Wq, qkv_b, Y, TDIM, DIM,
                                                          TDIM / 256);
  rope_qk2<<<SEQ, 256, 0, stream>>>(Y, ct, st, Qr, Kr);
  vtrans3<<<dim3(NH, SEQ / 64), 256, 0, stream>>>(Y, Vp);
  attn7<<<512, 256, 0, stream>>>(Qr, Kr, Vp, Ob);
  gemm_bt<1><<<dim3(DIM / 128, SEQ / 128), 256, 0, stream>>>(Ob, Wp, proj_b, d_out, SEQ, DIM, DIM);
}

// Round 9
// 238.114 us; speedup vs baseline: 1.0312x; 1.0312x over previous
//
#include <hip/hip_runtime.h>

#define SEQ 4096
#define DIM 1280
#define NH 16
#define HD 80
#define HQ 96
#define TDIM 3840

// softmax scale (1/sqrt(80)) * log2(e), folded into Q at repack
#define QSC 0.16129842980505168f

typedef __bf16 bf16x8 __attribute__((ext_vector_type(8)));
typedef __bf16 bf16x4 __attribute__((ext_vector_type(4)));
typedef float f32x4 __attribute__((ext_vector_type(4)));

__device__ __forceinline__ unsigned short f2bf(float f) {
  unsigned int u = __builtin_bit_cast(unsigned int, f);
  u += 0x7FFF + ((u >> 16) & 1);
  return (unsigned short)(u >> 16);
}
__device__ __forceinline__ float bf2f(unsigned short b) {
  unsigned int u = ((unsigned int)b) << 16;
  return __builtin_bit_cast(float, u);
}
__device__ __forceinline__ unsigned int cvtpk(float a, float b) {
  unsigned int r;
  asm("v_cvt_pk_bf16_f32 %0, %1, %2" : "=v"(r) : "v"(a), "v"(b));
  return r;
}

__device__ __forceinline__ void gload_lds16(const void* g, void* l) {
  __builtin_amdgcn_global_load_lds(
      (const __attribute__((address_space(1))) unsigned int*)g,
      (__attribute__((address_space(3))) unsigned int*)l, 16, 0, 0);
}

// ---------------- fused prep: fp32->bf16 x3 + cos/sin table ----------------
__global__ __launch_bounds__(256) void prep(const float* __restrict__ X,
                                            const float* __restrict__ Wq,
                                            const float* __restrict__ Wp,
                                            const float* __restrict__ rope,
                                            unsigned short* __restrict__ Xb,
                                            unsigned short* __restrict__ Wqb,
                                            unsigned short* __restrict__ Wpb,
                                            float* __restrict__ ct, float* __restrict__ st) {
  constexpr int N0 = SEQ * DIM / 4;
  constexpr int N1 = TDIM * DIM / 4;
  constexpr int N2 = DIM * DIM / 4;
  constexpr int N3 = SEQ * HD / 4;
  const int stride = gridDim.x * 256;
  for (int i = blockIdx.x * 256 + threadIdx.x; i < N0 + N1 + N2 + N3; i += stride) {
    if (i < N0 + N1 + N2) {
      const float4* src;
      unsigned short* dst;
      int j;
      if (i < N0) {
        src = (const float4*)X; dst = Xb; j = i;
      } else if (i < N0 + N1) {
        src = (const float4*)Wq; dst = Wqb; j = i - N0;
      } else {
        src = (const float4*)Wp; dst = Wpb; j = i - N0 - N1;
      }
      float4 f = src[j];
      ushort4 o;
      o.x = f2bf(f.x); o.y = f2bf(f.y); o.z = f2bf(f.z); o.w = f2bf(f.w);
      ((ushort4*)dst)[j] = o;
    } else {
      const int j = i - N0 - N1 - N2;
      float4 v = ((const float4*)rope)[j];
      float4 c, s;
      c.x = cosf(v.x); c.y = cosf(v.y); c.z = cosf(v.z); c.w = cosf(v.w);
      s.x = sinf(v.x); s.y = sinf(v.y); s.z = sinf(v.z); s.w = sinf(v.w);
      ((float4*)ct)[j] = c;
      ((float4*)st)[j] = s;
    }
  }
}

// ---------------- GEMM: C = A(MxK) @ B(NxK)^T + bias (128^2, ring-2) ----------------
template <int F32OUT>
__global__ __launch_bounds__(256) void gemm_bt(const unsigned short* __restrict__ A,
                                               const unsigned short* __restrict__ B,
                                               const float* __restrict__ bias,
                                               void* __restrict__ Cout, int M, int N, int K) {
  __shared__ unsigned short As[2][4096];
  __shared__ unsigned short Bs[2][4096];
  const int t = threadIdx.x;
  const int l = t & 63, w = t >> 6;
  const int row16 = l & 15, kg = l >> 4;
  const int brow = blockIdx.y * 128, bcol = blockIdx.x * 128;
  const int wr = w >> 1, wc = w & 1;
  f32x4 acc[4][4] = {};
  const size_t Ks = (size_t)K;
  const unsigned short* Ag = A + (brow + (t >> 2)) * Ks + (t & 3) * 8;
  const unsigned short* Bg = B + (bcol + (t >> 2)) * Ks + (t & 3) * 8;
  const int woff = w * 512;
  const int nk = K >> 5;

  auto SG = [&](int kt, int b) {
    const unsigned short* a = Ag + kt * 32;
    const unsigned short* bp = Bg + kt * 32;
    gload_lds16(a, &As[b][woff]);
    gload_lds16(a + 64 * Ks, &As[b][woff + 2048]);
    gload_lds16(bp, &Bs[b][woff]);
    gload_lds16(bp + 64 * Ks, &Bs[b][woff + 2048]);
  };
  auto COMP = [&](int b) {
    bf16x8 af[4], bfr[4];
#pragma unroll
    for (int m = 0; m < 4; ++m)
      af[m] = *(const bf16x8*)&As[b][(wr * 64 + m * 16 + row16) * 32 + kg * 8];
#pragma unroll
    for (int n = 0; n < 4; ++n)
      bfr[n] = *(const bf16x8*)&Bs[b][(wc * 64 + n * 16 + row16) * 32 + kg * 8];
#pragma unroll
    for (int m = 0; m < 4; ++m)
#pragma unroll
      for (int n = 0; n < 4; ++n)
        acc[m][n] = __builtin_amdgcn_mfma_f32_16x16x32_bf16(af[m], bfr[n], acc[m][n], 0, 0, 0);
  };

  SG(0, 0);
#pragma unroll 1
  for (int kt = 0; kt < nk - 1; ++kt) {
    SG(kt + 1, (kt + 1) & 1);
    asm volatile("s_waitcnt vmcnt(4)" ::: "memory");
    __builtin_amdgcn_s_barrier();
    __builtin_amdgcn_sched_barrier(0);
    COMP(kt & 1);
    asm volatile("" ::: "memory");
    __builtin_amdgcn_s_barrier();
  }
  asm volatile("s_waitcnt vmcnt(0)" ::: "memory");
  __builtin_amdgcn_s_barrier();
  __builtin_amdgcn_sched_barrier(0);
  COMP((nk - 1) & 1);

#pragma unroll
  for (int n = 0; n < 4; ++n) {
    const int col = bcol + wc * 64 + n * 16 + row16;
    const float bv = bias[col];
#pragma unroll
    for (int m = 0; m < 4; ++m) {
      const int row = brow + wr * 64 + m * 16 + kg * 4;
#pragma unroll
      for (int r = 0; r < 4; ++r) {
        float v = acc[m][n][r] + bv;
        if (F32OUT)
          ((float*)Cout)[(size_t)(row + r) * N + col] = v;
        else
          ((unsigned short*)Cout)[(size_t)(row + r) * N + col] = f2bf(v);
      }
    }
  }
}

// ---------------- RoPE + repack Q,K -> [h][s][96]; Q pre-scaled ----------------
__global__ __launch_bounds__(256) void rope_qk2(const unsigned short* __restrict__ Y,
                                                const float* __restrict__ ct,
                                                const float* __restrict__ st,
                                                unsigned short* __restrict__ Qr,
                                                unsigned short* __restrict__ Kr) {
  const int s = blockIdx.x, tid = threadIdx.x;
  const unsigned short* yq = Y + (size_t)s * TDIM;
  const unsigned short* yk = yq + DIM;
  for (int i = tid; i < 640; i += 256) {
    const int h = i / 40, j = i - h * 40;
    const float c0 = ct[s * HD + j], c1 = ct[s * HD + j + 40];
    const float s0 = st[s * HD + j], s1 = st[s * HD + j + 40];
    const float q0 = bf2f(yq[h * HD + j]), q1 = bf2f(yq[h * HD + j + 40]);
    const float k0 = bf2f(yk[h * HD + j]), k1 = bf2f(yk[h * HD + j + 40]);
    const size_t o = ((size_t)h * SEQ + s) * HQ;
    Qr[o + j] = f2bf((q0 * c0 - q1 * s0) * QSC);
    Qr[o + j + 40] = f2bf((q1 * c1 + q0 * s1) * QSC);
    Kr[o + j] = f2bf(k0 * c0 - k1 * s0);
    Kr[o + j + 40] = f2bf(k1 * c1 + k0 * s1);
  }
  {  // zero pad d = 80..95 for all 16 heads
    const int h = tid >> 4, dp = 80 + (tid & 15);
    const size_t o = ((size_t)h * SEQ + s) * HQ + dp;
    Qr[o] = 0;
    Kr[o] = 0;
  }
}

// ---------------- V transpose -> permuted image Vp[h][d][4096] ----------------
__global__ __launch_bounds__(256) void vtrans3(const unsigned short* __restrict__ Y,
                                               unsigned short* __restrict__ Vp) {
  __shared__ unsigned short tile[64][128];
  const int h = blockIdx.x, s0 = blockIdx.y * 64, tid = threadIdx.x;
  const unsigned short* src = Y + 2 * DIM + h * HD;
  for (int u = tid; u < 640; u += 256) {
    const int s = u / 10, j = u - s * 10;
    uint4 v = *(const uint4*)(src + (size_t)(s0 + s) * TDIM + j * 8);
    *(uint4*)&tile[s][(j ^ ((s >> 3) & 7)) << 3] = v;
  }
  __syncthreads();
  for (int u = tid; u < 640; u += 256) {
    const int d = u >> 3, g = u & 7;
    const int gl = g ^ (d & 7);
    const int base_s = (gl & 1) * 32 + (gl >> 1) * 4;
    unsigned short tmp[8];
#pragma unroll
    for (int sub = 0; sub < 8; ++sub) {
      const int s = base_s + (sub >> 2) * 16 + (sub & 3);
      tmp[sub] = tile[s][(((d >> 3) ^ ((s >> 3) & 7)) << 3) + (d & 7)];
    }
    *(uint4*)(Vp + (size_t)(h * HD + d) * SEQ + s0 + g * 8) = *(uint4*)tmp;
  }
}

// ---------------- Flash attention v8: ring-3 counted vmcnt + 1-deep PV pipeline ----
// Per region: QK(t) MFMAs + PV(t-1) MFMAs (register-held P,V) overlap SM(t) VALU.
__global__ __launch_bounds__(256, 2) void attn8(const unsigned short* __restrict__ Qr,
                                                const unsigned short* __restrict__ Kr,
                                                const unsigned short* __restrict__ Vp,
                                                unsigned short* __restrict__ Ob) {
  constexpr int KBYT = 12288;
  constexpr int VBYT = 10240;
  constexpr int BUFB = KBYT + VBYT;  // 22528
  constexpr int NT = SEQ / 64;       // 64 tiles
  __shared__ char smem[3 * BUFB];

  const int tid = threadIdx.x;
  const int l = tid & 63, w = tid >> 6;
  const int row16 = l & 15, kg = l >> 4;
  const int bid = blockIdx.x;
  const int h = bid & 15;
  const int q0 = (bid >> 4) * 128 + w * 32;
  const size_t hs = (size_t)h * SEQ;
  const bool loww = (w < 2);

  const unsigned short* Qh = Qr + hs * HQ;
  const char* Kh = (const char*)(Kr + hs * HQ);
  const char* Vh = (const char*)(Vp + (size_t)h * HD * SEQ);

  // staging: 1408 16B-units (768 K + 640 V); unit u = tid + 256*i
  unsigned soff[6], sdst[6];
  bool isk[6];
  const int cnt = (tid < 128) ? 6 : 5;
#pragma unroll
  for (int i = 0; i < 6; ++i) {
    const int u = tid + 256 * i;
    if (u < 768) {
      soff[i] = (u & 63) * 192 + (u >> 6) * 16;
      isk[i] = true;
    } else {
      const int v = u - 768;
      soff[i] = (v >> 3) * 8192 + (v & 7) * 16;
      isk[i] = false;
    }
    sdst[i] = u << 4;
  }
  auto STAGE = [&](int t, int bb) {
    const char* kb = Kh + (size_t)t * 12288;
    const char* vb = Vh + (size_t)t * 128;
#pragma unroll
    for (int i = 0; i < 6; ++i)
      if (i < cnt) gload_lds16((isk[i] ? kb : vb) + soff[i], smem + bb + sdst[i]);
  };

  // LDS read bases (tile-invariant)
  const int kbase = row16 * 16;  // + (4c+kg)*1024 + nb*256
  int vb_[2];
#pragma unroll
  for (int ks = 0; ks < 2; ++ks)
    vb_[ks] = KBYT + row16 * 128 + ((((kg << 1) | ks) ^ (row16 & 7)) << 4);  // + n5*2048

  // Q fragments (B-operand of swapped QK^T): q = q0 + qb*16 + row16
  bf16x8 qf[2][3];
#pragma unroll
  for (int qb = 0; qb < 2; ++qb)
#pragma unroll
    for (int c = 0; c < 3; ++c)
      qf[qb][c] = *(const bf16x8*)&Qh[(size_t)(q0 + qb * 16 + row16) * HQ + c * 32 + kg * 8];
  // Force the compiler's vmcnt wait for qf HERE (pre-pipeline), not inside the loop.
  asm volatile("" ::"v"(qf[0][0]), "v"(qf[0][1]), "v"(qf[0][2]));
  asm volatile("" ::"v"(qf[1][0]), "v"(qf[1][1]), "v"(qf[1][2]));

  union { bf16x8 v; unsigned int u[4]; } ones;
  ones.u[0] = ones.u[1] = ones.u[2] = ones.u[3] = 0x3F803F80u;

  float m_run[2] = {-3.0e38f, -3.0e38f};
  f32x4 oacc[2][6] = {};  // [qb][d-block 0..4, 5 = row-sum l]

  // pipeline state: packed P and V fragments of the previous tile (A/B sets)
  unsigned pfA[2][2][4], pfB[2][2][4];
  bf16x8 vfA[5][2], vfB[5][2];

  // PV of a previous tile: pure register MFMA (no LDS) -> can overlap SM of cur tile
  auto PV = [&](const unsigned (&pfi)[2][2][4], const bf16x8 (&vfi)[5][2]) {
    __builtin_amdgcn_s_setprio(1);
#pragma unroll
    for (int qb = 0; qb < 2; ++qb)
#pragma unroll
      for (int ks = 0; ks < 2; ++ks) {
        union { bf16x8 v; unsigned int u[4]; } pf;
        pf.u[0] = pfi[qb][ks][0];
        pf.u[1] = pfi[qb][ks][1];
        pf.u[2] = pfi[qb][ks][2];
        pf.u[3] = pfi[qb][ks][3];
#pragma unroll
        for (int n5 = 0; n5 < 5; ++n5)
          oacc[qb][n5] =
              __builtin_amdgcn_mfma_f32_16x16x32_bf16(vfi[n5][ks], pf.v, oacc[qb][n5], 0, 0, 0);
        oacc[qb][5] = __builtin_amdgcn_mfma_f32_16x16x32_bf16(ones.v, pf.v, oacc[qb][5], 0, 0, 0);
      }
    __builtin_amdgcn_s_setprio(0);
  };

  // One pipeline step: QK(t) -> SM(t) -> pack into pfo; V(t) -> vfo; PV(t-1) from pfi/vfi.
  auto STEP = [&](const char* B, unsigned (&pfo)[2][2][4], bf16x8 (&vfo)[5][2],
                  const unsigned (&pfi)[2][2][4], const bf16x8 (&vfi)[5][2], bool dopv) {
    // ---- QK^T: per d-chunk c, load 4 K-frags then 8 MFMAs ----
    f32x4 sacc[2][4] = {};
#pragma unroll
    for (int c = 0; c < 3; ++c) {
      bf16x8 kf[4];
      const char* kc = B + (4 * c + kg) * 1024 + kbase;
#pragma unroll
      for (int nb = 0; nb < 4; ++nb) kf[nb] = *(const bf16x8*)(kc + nb * 256);
      __builtin_amdgcn_s_setprio(1);
#pragma unroll
      for (int qb = 0; qb < 2; ++qb)
#pragma unroll
        for (int nb = 0; nb < 4; ++nb)
          sacc[qb][nb] =
              __builtin_amdgcn_mfma_f32_16x16x32_bf16(kf[nb], qf[qb][c], sacc[qb][nb], 0, 0, 0);
      __builtin_amdgcn_s_setprio(0);
    }
    // ---- V fragments of tile t -> registers (held until next region) ----
#pragma unroll
    for (int n5 = 0; n5 < 5; ++n5)
#pragma unroll
      for (int ks = 0; ks < 2; ++ks) vfo[n5][ks] = *(const bf16x8*)(B + vb_[ks] + n5 * 2048);
    // ---- PV of previous tile (independent of SM below -> co-issues with it) ----
    if (dopv) PV(pfi, vfi);
    // ---- softmax: per-lane local max; cross-lane ONLY when threshold exceeded ----
    float pl[2];
#pragma unroll
    for (int qb = 0; qb < 2; ++qb) {
      float a0 = fmaxf(fmaxf(sacc[qb][0][0], sacc[qb][0][1]), fmaxf(sacc[qb][0][2], sacc[qb][0][3]));
      float a1 = fmaxf(fmaxf(sacc[qb][1][0], sacc[qb][1][1]), fmaxf(sacc[qb][1][2], sacc[qb][1][3]));
      float a2 = fmaxf(fmaxf(sacc[qb][2][0], sacc[qb][2][1]), fmaxf(sacc[qb][2][2], sacc[qb][2][3]));
      float a3 = fmaxf(fmaxf(sacc[qb][3][0], sacc[qb][3][1]), fmaxf(sacc[qb][3][2], sacc[qb][3][3]));
      pl[qb] = fmaxf(fmaxf(a0, a1), fmaxf(a2, a3));
    }
    // fast path: no lane's local max grew past m_run + 8 -> keep m_run, P <= 2^8
    if (!__all((pl[0] - m_run[0] <= 8.0f) & (pl[1] - m_run[1] <= 8.0f))) {
#pragma unroll
      for (int qb = 0; qb < 2; ++qb) {
        float m0 = pl[qb];
        m0 = fmaxf(m0, __shfl_xor(m0, 16, 64));
        m0 = fmaxf(m0, __shfl_xor(m0, 32, 64));
        const float mn = fmaxf(m_run[qb], m0);
        const float fac = __builtin_amdgcn_exp2f(m_run[qb] - mn);
        m_run[qb] = mn;
        // RAW dep on oacc orders this after PV(t-1) above -- correct rescale point
#pragma unroll
        for (int n6 = 0; n6 < 6; ++n6)
#pragma unroll
          for (int r = 0; r < 4; ++r) oacc[qb][n6][r] *= fac;
      }
    }
#pragma unroll
    for (int qb = 0; qb < 2; ++qb)
#pragma unroll
      for (int nb = 0; nb < 4; ++nb)
#pragma unroll
        for (int r = 0; r < 4; ++r)
          sacc[qb][nb][r] = __builtin_amdgcn_exp2f(sacc[qb][nb][r] - m_run[qb]);
    // ---- pack P -> bf16 fragments (k-map matches Vp image) ----
#pragma unroll
    for (int qb = 0; qb < 2; ++qb)
#pragma unroll
      for (int ks = 0; ks < 2; ++ks) {
        pfo[qb][ks][0] = cvtpk(sacc[qb][2 * ks][0], sacc[qb][2 * ks][1]);
        pfo[qb][ks][1] = cvtpk(sacc[qb][2 * ks][2], sacc[qb][2 * ks][3]);
        pfo[qb][ks][2] = cvtpk(sacc[qb][2 * ks + 1][0], sacc[qb][2 * ks + 1][1]);
        pfo[qb][ks][3] = cvtpk(sacc[qb][2 * ks + 1][2], sacc[qb][2 * ks + 1][3]);
      }
  };

  // ---- prologue: fill stages for tiles 0 and 1 ----
  STAGE(0, 0);
  STAGE(1, BUFB);

  // iter 0 (even -> set A), no PV
  STAGE(2, 2 * BUFB);
  if (loww)
    asm volatile("s_waitcnt vmcnt(12)" ::: "memory");
  else
    asm volatile("s_waitcnt vmcnt(10)" ::: "memory");
  __builtin_amdgcn_s_barrier();
  __builtin_amdgcn_sched_barrier(0);
  STEP(smem + 0, pfA, vfA, pfB, vfB, false);
  asm volatile("" ::: "memory");
  __builtin_amdgcn_s_barrier();

  int cur = 1;  // buffer index of the tile being computed
  // iters 1..60 as 30 unrolled pairs (odd -> B, even -> A)
#pragma unroll 1
  for (int tp = 1; tp <= 59; tp += 2) {
    // iter tp (odd): FRONT B, PV from A
    int sb = (cur == 0) ? 2 : (cur - 1);
    STAGE(tp + 2, sb * BUFB);
    if (loww)
      asm volatile("s_waitcnt vmcnt(12)" ::: "memory");
    else
      asm volatile("s_waitcnt vmcnt(10)" ::: "memory");
    __builtin_amdgcn_s_barrier();
    __builtin_amdgcn_sched_barrier(0);
    STEP(smem + cur * BUFB, pfB, vfB, pfA, vfA, true);
    asm volatile("" ::: "memory");
    __builtin_amdgcn_s_barrier();
    cur = (cur == 2) ? 0 : (cur + 1);
    // iter tp+1 (even): FRONT A, PV from B
    sb = (cur == 0) ? 2 : (cur - 1);
    STAGE(tp + 3, sb * BUFB);
    if (loww)
      asm volatile("s_waitcnt vmcnt(12)" ::: "memory");
    else
      asm volatile("s_waitcnt vmcnt(10)" ::: "memory");
    __builtin_amdgcn_s_barrier();
    __builtin_amdgcn_sched_barrier(0);
    STEP(smem + cur * BUFB, pfA, vfA, pfB, vfB, true);
    asm volatile("" ::: "memory");
    __builtin_amdgcn_s_barrier();
    cur = (cur == 2) ? 0 : (cur + 1);
  }
  // iter 61 (odd): stage tile 63, FRONT B, PV from A
  {
    int sb = (cur == 0) ? 2 : (cur - 1);
    STAGE(63, sb * BUFB);
    if (loww)
      asm volatile("s_waitcnt vmcnt(12)" ::: "memory");
    else
      asm volatile("s_waitcnt vmcnt(10)" ::: "memory");
    __builtin_amdgcn_s_barrier();
    __builtin_amdgcn_sched_barrier(0);
    STEP(smem + cur * BUFB, pfB, vfB, pfA, vfA, true);
    asm volatile("" ::: "memory");
    __builtin_amdgcn_s_barrier();
    cur = (cur == 2) ? 0 : (cur + 1);
  }
  // iter 62 (even): one stage (63) still in flight
  if (loww)
    asm volatile("s_waitcnt vmcnt(6)" ::: "memory");
  else
    asm volatile("s_waitcnt vmcnt(5)" ::: "memory");
  __builtin_amdgcn_s_barrier();
  __builtin_amdgcn_sched_barrier(0);
  STEP(smem + cur * BUFB, pfA, vfA, pfB, vfB, true);
  asm volatile("" ::: "memory");
  __builtin_amdgcn_s_barrier();
  cur = (cur == 2) ? 0 : (cur + 1);
  // iter 63 (odd): drain fully
  asm volatile("s_waitcnt vmcnt(0)" ::: "memory");
  __builtin_amdgcn_s_barrier();
  __builtin_amdgcn_sched_barrier(0);
  STEP(smem + cur * BUFB, pfB, vfB, pfA, vfA, true);
  // final PV of tile 63
  PV(pfB, vfB);

  // ---- epilogue: d = n5*16 + kg*4 + r, q = q0 + qb*16 + row16 ----
#pragma unroll
  for (int qb = 0; qb < 2; ++qb) {
    const float rl = 1.0f / oacc[qb][5][0];
    unsigned short* orow = Ob + (size_t)(q0 + qb * 16 + row16) * DIM + h * HD + kg * 4;
#pragma unroll
    for (int n5 = 0; n5 < 5; ++n5) {
      ushort4 o;
      o.x = f2bf(oacc[qb][n5][0] * rl);
      o.y = f2bf(oacc[qb][n5][1] * rl);
      o.z = f2bf(oacc[qb][n5][2] * rl);
      o.w = f2bf(oacc[qb][n5][3] * rl);
      *(ushort4*)(orow + n5 * 16) = o;
    }
  }
}

// ---------------- host ----------------
extern "C" void kernel_launch(void* const* d_in, const int* in_sizes, int n_in, void* d_out,
                              int out_size, void* d_ws, size_t ws_size, hipStream_t stream) {
  (void)in_sizes; (void)n_in; (void)out_size; (void)ws_size;
  const float* hidden = (const float*)d_in[0];
  const float* rope = (const float*)d_in[2];
  const float* qkv_w = (const float*)d_in[3];
  const float* qkv_b = (const float*)d_in[4];
  const float* proj_w = (const float*)d_in[5];
  const float* proj_b = (const float*)d_in[6];

  char* p = (char*)d_ws;
  unsigned short* Xb = (unsigned short*)p;       p += (size_t)SEQ * DIM * 2;
  unsigned short* Wq = (unsigned short*)p;       p += (size_t)TDIM * DIM * 2;
  unsigned short* Wp = (unsigned short*)p;       p += (size_t)DIM * DIM * 2;
  float* ct = (float*)p;                         p += (size_t)SEQ * HD * 4;
  float* st = (float*)p;                         p += (size_t)SEQ * HD * 4;
  unsigned short* Y = (unsigned short*)p;        p += (size_t)SEQ * TDIM * 2;
  unsigned short* Qr = (unsigned short*)p;       p += (size_t)NH * SEQ * HQ * 2;
  unsigned short* Kr = (unsigned short*)p;       p += (size_t)NH * SEQ * HQ * 2;
  unsigned short* Vp = (unsigned short*)p;       p += (size_t)NH * HD * SEQ * 2;
  unsigned short* Ob = (unsigned short*)p;       p += (size_t)SEQ * DIM * 2;

  prep<<<2048, 256, 0, stream>>>(hidden, qkv_w, proj_w, rope, Xb, Wq, Wp, ct, st);
  gemm_bt<0><<<dim3(TDIM / 128, SEQ / 128), 256, 0, stream>>>(Xb, Wq, qkv_b, Y, SEQ, TDIM, DIM);
  rope_qk2<<<SEQ, 256, 0, stream>>>(Y, ct, st, Qr, Kr);
  vtrans3<<<dim3(NH, SEQ / 64), 256, 0, stream>>>(Y, Vp);
  attn8<<<512, 256, 0, stream>>>(Qr, Kr, Vp, Ob);
  gemm_bt<1><<<dim3(DIM / 128, SEQ / 128), 256, 0, stream>>>(Ob, Wp, proj_b, d_out, SEQ, DIM, DIM);
}

// Round 10
// 216.912 us; speedup vs baseline: 1.1320x; 1.0977x over previous
//
#include <hip/hip_runtime.h>

#define SEQ 4096
#define DIM 1280
#define NH 16
#define HD 80
#define HQ 96
#define TDIM 3840

// softmax scale (1/sqrt(80)) * log2(e), folded into Q at repack
#define QSC 0.16129842980505168f

typedef __bf16 bf16x8 __attribute__((ext_vector_type(8)));
typedef __bf16 bf16x4 __attribute__((ext_vector_type(4)));
typedef float f32x4 __attribute__((ext_vector_type(4)));

__device__ __forceinline__ unsigned short f2bf(float f) {
  unsigned int u = __builtin_bit_cast(unsigned int, f);
  u += 0x7FFF + ((u >> 16) & 1);
  return (unsigned short)(u >> 16);
}
__device__ __forceinline__ float bf2f(unsigned short b) {
  unsigned int u = ((unsigned int)b) << 16;
  return __builtin_bit_cast(float, u);
}
__device__ __forceinline__ unsigned int cvtpk(float a, float b) {
  unsigned int r;
  asm("v_cvt_pk_bf16_f32 %0, %1, %2" : "=v"(r) : "v"(a), "v"(b));
  return r;
}

__device__ __forceinline__ void gload_lds16(const void* g, void* l) {
  __builtin_amdgcn_global_load_lds(
      (const __attribute__((address_space(1))) unsigned int*)g,
      (__attribute__((address_space(3))) unsigned int*)l, 16, 0, 0);
}

// ---------------- fused prep: fp32->bf16 x3 + cos/sin table ----------------
__global__ __launch_bounds__(256) void prep(const float* __restrict__ X,
                                            const float* __restrict__ Wq,
                                            const float* __restrict__ Wp,
                                            const float* __restrict__ rope,
                                            unsigned short* __restrict__ Xb,
                                            unsigned short* __restrict__ Wqb,
                                            unsigned short* __restrict__ Wpb,
                                            float* __restrict__ ct, float* __restrict__ st) {
  constexpr int N0 = SEQ * DIM / 4;
  constexpr int N1 = TDIM * DIM / 4;
  constexpr int N2 = DIM * DIM / 4;
  constexpr int N3 = SEQ * HD / 4;
  const int stride = gridDim.x * 256;
  for (int i = blockIdx.x * 256 + threadIdx.x; i < N0 + N1 + N2 + N3; i += stride) {
    if (i < N0 + N1 + N2) {
      const float4* src;
      unsigned short* dst;
      int j;
      if (i < N0) {
        src = (const float4*)X; dst = Xb; j = i;
      } else if (i < N0 + N1) {
        src = (const float4*)Wq; dst = Wqb; j = i - N0;
      } else {
        src = (const float4*)Wp; dst = Wpb; j = i - N0 - N1;
      }
      float4 f = src[j];
      ushort4 o;
      o.x = f2bf(f.x); o.y = f2bf(f.y); o.z = f2bf(f.z); o.w = f2bf(f.w);
      ((ushort4*)dst)[j] = o;
    } else {
      const int j = i - N0 - N1 - N2;
      float4 v = ((const float4*)rope)[j];
      float4 c, s;
      c.x = cosf(v.x); c.y = cosf(v.y); c.z = cosf(v.z); c.w = cosf(v.w);
      s.x = sinf(v.x); s.y = sinf(v.y); s.z = sinf(v.z); s.w = sinf(v.w);
      ((float4*)ct)[j] = c;
      ((float4*)st)[j] = s;
    }
  }
}

// ---------------- QKV GEMM: 256x256 tile, BK=64, 4-phase interleave ----------------
// C(4096x3840) = A(4096x1280) @ B(3840x1280)^T + bias, bf16 out.
// 8 waves (2M x 4N), per-wave 128x64 out. LDS: dbuf x (A 32KB + B 32KB) = 128KB.
// Swizzle: byte-col ^= (row&7)<<4 on ds_read; inverse-swizzled gload sources.
// vmcnt(2) at tile top only (part-0 of next tile stays in flight); per-phase
// barriers + setprio around each 16-MFMA cluster (T3+T4+T5, m201 regime).
__global__ __launch_bounds__(512, 1) void gemmq(const unsigned short* __restrict__ A,
                                                const unsigned short* __restrict__ B,
                                                const float* __restrict__ bias,
                                                unsigned short* __restrict__ Cout) {
  __shared__ char smem[131072];
  const int tid = threadIdx.x;
  const int l = tid & 63, w = tid >> 6;
  const int row16 = l & 15, kg = l >> 4;
  const int wr = w >> 2, wc = w & 3;

  // bijective XCD swizzle: grid 240 = 16 x 15, 240 % 8 == 0
  const int bid = blockIdx.x;
  const int swz = (bid & 7) * 30 + (bid >> 3);
  const int ny = swz / 15, nx = swz - ny * 15;
  const int brow = ny * 256, bcol = nx * 256;

  constexpr int Kb = 2560;  // global row stride bytes (K=1280)
  const char* Ag = (const char*)A + (size_t)brow * Kb;
  const char* Bg = (const char*)B + (size_t)bcol * Kb;

  // staging: per matrix 2048 16B-units; wave w, instr i covers units (w*4+i)*64+lane.
  // LDS granule cg holds global granule cg ^ (row&7)  (XOR involution).
  unsigned soff[4], sdst[4];
#pragma unroll
  for (int i = 0; i < 4; ++i) {
    const int u = ((w * 4 + i) << 6) + l;
    const int row = u >> 3;
    const int cg = (u & 7) ^ (row & 7);
    soff[i] = row * Kb + cg * 16;
    sdst[i] = u * 16;
  }
  auto SGA = [&](int kt, int b, int i) {
    gload_lds16(Ag + kt * 128 + soff[i], smem + b * 65536 + sdst[i]);
  };
  auto SGB = [&](int kt, int b, int i) {
    gload_lds16(Bg + kt * 128 + soff[i], smem + b * 65536 + 32768 + sdst[i]);
  };

  f32x4 acc[8][4] = {};
  const int arow = (wr * 128 + row16) * 128;
  const int brow_ = (wc * 64 + row16) * 128;
  int cswz[2];
#pragma unroll
  for (int ks = 0; ks < 2; ++ks) cswz[ks] = (ks * 64 + kg * 16) ^ ((row16 & 7) << 4);

  // prologue: stage tile 0 fully
#pragma unroll
  for (int i = 0; i < 4; ++i) SGA(0, 0, i);
#pragma unroll
  for (int i = 0; i < 4; ++i) SGB(0, 0, i);

  constexpr int NKT = 20;  // K / 64
#pragma unroll 1
  for (int t = 0; t < NKT; ++t) {
    const int cb = t & 1, nb2 = cb ^ 1;
    const bool more = (t + 1 < NKT);
    if (more) {
      SGA(t + 1, nb2, 0);
      SGB(t + 1, nb2, 0);
      asm volatile("s_waitcnt vmcnt(2)" ::: "memory");
    } else {
      asm volatile("s_waitcnt vmcnt(0)" ::: "memory");
    }
    __builtin_amdgcn_s_barrier();
    __builtin_amdgcn_sched_barrier(0);
    const char* Ab = smem + cb * 65536;
    const char* Bb = Ab + 32768;

    bf16x8 bf0[4], af[4];
    // ---- phase 0: ks=0, mi 0-3 ----
#pragma unroll
    for (int ni = 0; ni < 4; ++ni) bf0[ni] = *(const bf16x8*)(Bb + brow_ + ni * 2048 + cswz[0]);
#pragma unroll
    for (int m4 = 0; m4 < 4; ++m4) af[m4] = *(const bf16x8*)(Ab + arow + m4 * 2048 + cswz[0]);
    asm volatile("s_waitcnt lgkmcnt(0)" ::: "memory");
    __builtin_amdgcn_sched_barrier(0);
    __builtin_amdgcn_s_setprio(1);
#pragma unroll
    for (int m4 = 0; m4 < 4; ++m4)
#pragma unroll
      for (int ni = 0; ni < 4; ++ni)
        acc[m4][ni] = __builtin_amdgcn_mfma_f32_16x16x32_bf16(af[m4], bf0[ni], acc[m4][ni], 0, 0, 0);
    __builtin_amdgcn_s_setprio(0);
    __builtin_amdgcn_s_barrier();
    // ---- phase 1: ks=0, mi 4-7 ----
    if (more) { SGA(t + 1, nb2, 1); SGB(t + 1, nb2, 1); }
#pragma unroll
    for (int m4 = 0; m4 < 4; ++m4) af[m4] = *(const bf16x8*)(Ab + arow + (m4 + 4) * 2048 + cswz[0]);
    asm volatile("s_waitcnt lgkmcnt(0)" ::: "memory");
    __builtin_amdgcn_sched_barrier(0);
    __builtin_amdgcn_s_setprio(1);
#pragma unroll
    for (int m4 = 0; m4 < 4; ++m4)
#pragma unroll
      for (int ni = 0; ni < 4; ++ni)
        acc[m4 + 4][ni] =
            __builtin_amdgcn_mfma_f32_16x16x32_bf16(af[m4], bf0[ni], acc[m4 + 4][ni], 0, 0, 0);
    __builtin_amdgcn_s_setprio(0);
    __builtin_amdgcn_s_barrier();
    // ---- phase 2: ks=1, mi 0-3 ----
    if (more) { SGA(t + 1, nb2, 2); SGB(t + 1, nb2, 2); }
#pragma unroll
    for (int ni = 0; ni < 4; ++ni) bf0[ni] = *(const bf16x8*)(Bb + brow_ + ni * 2048 + cswz[1]);
#pragma unroll
    for (int m4 = 0; m4 < 4; ++m4) af[m4] = *(const bf16x8*)(Ab + arow + m4 * 2048 + cswz[1]);
    asm volatile("s_waitcnt lgkmcnt(0)" ::: "memory");
    __builtin_amdgcn_sched_barrier(0);
    __builtin_amdgcn_s_setprio(1);
#pragma unroll
    for (int m4 = 0; m4 < 4; ++m4)
#pragma unroll
      for (int ni = 0; ni < 4; ++ni)
        acc[m4][ni] = __builtin_amdgcn_mfma_f32_16x16x32_bf16(af[m4], bf0[ni], acc[m4][ni], 0, 0, 0);
    __builtin_amdgcn_s_setprio(0);
    __builtin_amdgcn_s_barrier();
    // ---- phase 3: ks=1, mi 4-7 ----
    if (more) { SGA(t + 1, nb2, 3); SGB(t + 1, nb2, 3); }
#pragma unroll
    for (int m4 = 0; m4 < 4; ++m4) af[m4] = *(const bf16x8*)(Ab + arow + (m4 + 4) * 2048 + cswz[1]);
    asm volatile("s_waitcnt lgkmcnt(0)" ::: "memory");
    __builtin_amdgcn_sched_barrier(0);
    __builtin_amdgcn_s_setprio(1);
#pragma unroll
    for (int m4 = 0; m4 < 4; ++m4)
#pragma unroll
      for (int ni = 0; ni < 4; ++ni)
        acc[m4 + 4][ni] =
            __builtin_amdgcn_mfma_f32_16x16x32_bf16(af[m4], bf0[ni], acc[m4 + 4][ni], 0, 0, 0);
    __builtin_amdgcn_s_setprio(0);
    __builtin_amdgcn_s_barrier();
  }

  // ---- epilogue: row = brow + wr*128 + mi*16 + kg*4 + r; col = bcol + wc*64 + ni*16 + row16
#pragma unroll
  for (int ni = 0; ni < 4; ++ni) {
    const int col = bcol + wc * 64 + ni * 16 + row16;
    const float bv = bias[col];
#pragma unroll
    for (int mi = 0; mi < 8; ++mi) {
      const int row = brow + wr * 128 + mi * 16 + kg * 4;
#pragma unroll
      for (int r = 0; r < 4; ++r)
        Cout[(size_t)(row + r) * TDIM + col] = f2bf(acc[mi][ni][r] + bv);
    }
  }
}

// ---------------- GEMM: C = A(MxK) @ B(NxK)^T + bias (128^2, ring-2) ----------------
template <int F32OUT>
__global__ __launch_bounds__(256) void gemm_bt(const unsigned short* __restrict__ A,
                                               const unsigned short* __restrict__ B,
                                               const float* __restrict__ bias,
                                               void* __restrict__ Cout, int M, int N, int K) {
  __shared__ unsigned short As[2][4096];
  __shared__ unsigned short Bs[2][4096];
  const int t = threadIdx.x;
  const int l = t & 63, w = t >> 6;
  const int row16 = l & 15, kg = l >> 4;
  const int brow = blockIdx.y * 128, bcol = blockIdx.x * 128;
  const int wr = w >> 1, wc = w & 1;
  f32x4 acc[4][4] = {};
  const size_t Ks = (size_t)K;
  const unsigned short* Ag = A + (brow + (t >> 2)) * Ks + (t & 3) * 8;
  const unsigned short* Bg = B + (bcol + (t >> 2)) * Ks + (t & 3) * 8;
  const int woff = w * 512;
  const int nk = K >> 5;

  auto SG = [&](int kt, int b) {
    const unsigned short* a = Ag + kt * 32;
    const unsigned short* bp = Bg + kt * 32;
    gload_lds16(a, &As[b][woff]);
    gload_lds16(a + 64 * Ks, &As[b][woff + 2048]);
    gload_lds16(bp, &Bs[b][woff]);
    gload_lds16(bp + 64 * Ks, &Bs[b][woff + 2048]);
  };
  auto COMP = [&](int b) {
    bf16x8 af[4], bfr[4];
#pragma unroll
    for (int m = 0; m < 4; ++m)
      af[m] = *(const bf16x8*)&As[b][(wr * 64 + m * 16 + row16) * 32 + kg * 8];
#pragma unroll
    for (int n = 0; n < 4; ++n)
      bfr[n] = *(const bf16x8*)&Bs[b][(wc * 64 + n * 16 + row16) * 32 + kg * 8];
#pragma unroll
    for (int m = 0; m < 4; ++m)
#pragma unroll
      for (int n = 0; n < 4; ++n)
        acc[m][n] = __builtin_amdgcn_mfma_f32_16x16x32_bf16(af[m], bfr[n], acc[m][n], 0, 0, 0);
  };

  SG(0, 0);
#pragma unroll 1
  for (int kt = 0; kt < nk - 1; ++kt) {
    SG(kt + 1, (kt + 1) & 1);
    asm volatile("s_waitcnt vmcnt(4)" ::: "memory");
    __builtin_amdgcn_s_barrier();
    __builtin_amdgcn_sched_barrier(0);
    COMP(kt & 1);
    asm volatile("" ::: "memory");
    __builtin_amdgcn_s_barrier();
  }
  asm volatile("s_waitcnt vmcnt(0)" ::: "memory");
  __builtin_amdgcn_s_barrier();
  __builtin_amdgcn_sched_barrier(0);
  COMP((nk - 1) & 1);

#pragma unroll
  for (int n = 0; n < 4; ++n) {
    const int col = bcol + wc * 64 + n * 16 + row16;
    const float bv = bias[col];
#pragma unroll
    for (int m = 0; m < 4; ++m) {
      const int row = brow + wr * 64 + m * 16 + kg * 4;
#pragma unroll
      for (int r = 0; r < 4; ++r) {
        float v = acc[m][n][r] + bv;
        if (F32OUT)
          ((float*)Cout)[(size_t)(row + r) * N + col] = v;
        else
          ((unsigned short*)Cout)[(size_t)(row + r) * N + col] = f2bf(v);
      }
    }
  }
}

// ---------------- RoPE + repack Q,K -> [h][s][96]; Q pre-scaled ----------------
__global__ __launch_bounds__(256) void rope_qk2(const unsigned short* __restrict__ Y,
                                                const float* __restrict__ ct,
                                                const float* __restrict__ st,
                                                unsigned short* __restrict__ Qr,
                                                unsigned short* __restrict__ Kr) {
  const int s = blockIdx.x, tid = threadIdx.x;
  const unsigned short* yq = Y + (size_t)s * TDIM;
  const unsigned short* yk = yq + DIM;
  for (int i = tid; i < 640; i += 256) {
    const int h = i / 40, j = i - h * 40;
    const float c0 = ct[s * HD + j], c1 = ct[s * HD + j + 40];
    const float s0 = st[s * HD + j], s1 = st[s * HD + j + 40];
    const float q0 = bf2f(yq[h * HD + j]), q1 = bf2f(yq[h * HD + j + 40]);
    const float k0 = bf2f(yk[h * HD + j]), k1 = bf2f(yk[h * HD + j + 40]);
    const size_t o = ((size_t)h * SEQ + s) * HQ;
    Qr[o + j] = f2bf((q0 * c0 - q1 * s0) * QSC);
    Qr[o + j + 40] = f2bf((q1 * c1 + q0 * s1) * QSC);
    Kr[o + j] = f2bf(k0 * c0 - k1 * s0);
    Kr[o + j + 40] = f2bf(k1 * c1 + k0 * s1);
  }
  {  // zero pad d = 80..95 for all 16 heads
    const int h = tid >> 4, dp = 80 + (tid & 15);
    const size_t o = ((size_t)h * SEQ + s) * HQ + dp;
    Qr[o] = 0;
    Kr[o] = 0;
  }
}

// ---------------- V transpose -> permuted image Vp[h][d][4096] ----------------
__global__ __launch_bounds__(256) void vtrans3(const unsigned short* __restrict__ Y,
                                               unsigned short* __restrict__ Vp) {
  __shared__ unsigned short tile[64][128];
  const int h = blockIdx.x, s0 = blockIdx.y * 64, tid = threadIdx.x;
  const unsigned short* src = Y + 2 * DIM + h * HD;
  for (int u = tid; u < 640; u += 256) {
    const int s = u / 10, j = u - s * 10;
    uint4 v = *(const uint4*)(src + (size_t)(s0 + s) * TDIM + j * 8);
    *(uint4*)&tile[s][(j ^ ((s >> 3) & 7)) << 3] = v;
  }
  __syncthreads();
  for (int u = tid; u < 640; u += 256) {
    const int d = u >> 3, g = u & 7;
    const int gl = g ^ (d & 7);
    const int base_s = (gl & 1) * 32 + (gl >> 1) * 4;
    unsigned short tmp[8];
#pragma unroll
    for (int sub = 0; sub < 8; ++sub) {
      const int s = base_s + (sub >> 2) * 16 + (sub & 3);
      tmp[sub] = tile[s][(((d >> 3) ^ ((s >> 3) & 7)) << 3) + (d & 7)];
    }
    *(uint4*)(Vp + (size_t)(h * HD + d) * SEQ + s0 + g * 8) = *(uint4*)tmp;
  }
}

// ---------------- Flash attention v8: ring-3 counted vmcnt + 1-deep PV pipeline ----
__global__ __launch_bounds__(256, 2) void attn8(const unsigned short* __restrict__ Qr,
                                                const unsigned short* __restrict__ Kr,
                                                const unsigned short* __restrict__ Vp,
                                                unsigned short* __restrict__ Ob) {
  constexpr int KBYT = 12288;
  constexpr int VBYT = 10240;
  constexpr int BUFB = KBYT + VBYT;  // 22528
  constexpr int NT = SEQ / 64;       // 64 tiles
  __shared__ char smem[3 * BUFB];

  const int tid = threadIdx.x;
  const int l = tid & 63, w = tid >> 6;
  const int row16 = l & 15, kg = l >> 4;
  const int bid = blockIdx.x;
  const int h = bid & 15;
  const int q0 = (bid >> 4) * 128 + w * 32;
  const size_t hs = (size_t)h * SEQ;
  const bool loww = (w < 2);

  const unsigned short* Qh = Qr + hs * HQ;
  const char* Kh = (const char*)(Kr + hs * HQ);
  const char* Vh = (const char*)(Vp + (size_t)h * HD * SEQ);

  // staging: 1408 16B-units (768 K + 640 V); unit u = tid + 256*i
  unsigned soff[6], sdst[6];
  bool isk[6];
  const int cnt = (tid < 128) ? 6 : 5;
#pragma unroll
  for (int i = 0; i < 6; ++i) {
    const int u = tid + 256 * i;
    if (u < 768) {
      soff[i] = (u & 63) * 192 + (u >> 6) * 16;
      isk[i] = true;
    } else {
      const int v = u - 768;
      soff[i] = (v >> 3) * 8192 + (v & 7) * 16;
      isk[i] = false;
    }
    sdst[i] = u << 4;
  }
  auto STAGE = [&](int t, int bb) {
    const char* kb = Kh + (size_t)t * 12288;
    const char* vb = Vh + (size_t)t * 128;
#pragma unroll
    for (int i = 0; i < 6; ++i)
      if (i < cnt) gload_lds16((isk[i] ? kb : vb) + soff[i], smem + bb + sdst[i]);
  };

  // LDS read bases (tile-invariant)
  const int kbase = row16 * 16;  // + (4c+kg)*1024 + nb*256
  int vb_[2];
#pragma unroll
  for (int ks = 0; ks < 2; ++ks)
    vb_[ks] = KBYT + row16 * 128 + ((((kg << 1) | ks) ^ (row16 & 7)) << 4);  // + n5*2048

  // Q fragments (B-operand of swapped QK^T): q = q0 + qb*16 + row16
  bf16x8 qf[2][3];
#pragma unroll
  for (int qb = 0; qb < 2; ++qb)
#pragma unroll
    for (int c = 0; c < 3; ++c)
      qf[qb][c] = *(const bf16x8*)&Qh[(size_t)(q0 + qb * 16 + row16) * HQ + c * 32 + kg * 8];
  // Force the compiler's vmcnt wait for qf HERE (pre-pipeline), not inside the loop.
  asm volatile("" ::"v"(qf[0][0]), "v"(qf[0][1]), "v"(qf[0][2]));
  asm volatile("" ::"v"(qf[1][0]), "v"(qf[1][1]), "v"(qf[1][2]));

  union { bf16x8 v; unsigned int u[4]; } ones;
  ones.u[0] = ones.u[1] = ones.u[2] = ones.u[3] = 0x3F803F80u;

  float m_run[2] = {-3.0e38f, -3.0e38f};
  f32x4 oacc[2][6] = {};  // [qb][d-block 0..4, 5 = row-sum l]

  // pipeline state: packed P and V fragments of the previous tile (A/B sets)
  unsigned pfA[2][2][4], pfB[2][2][4];
  bf16x8 vfA[5][2], vfB[5][2];

  // PV of a previous tile: pure register MFMA (no LDS) -> can overlap SM of cur tile
  auto PV = [&](const unsigned (&pfi)[2][2][4], const bf16x8 (&vfi)[5][2]) {
    __builtin_amdgcn_s_setprio(1);
#pragma unroll
    for (int qb = 0; qb < 2; ++qb)
#pragma unroll
      for (int ks = 0; ks < 2; ++ks) {
        union { bf16x8 v; unsigned int u[4]; } pf;
        pf.u[0] = pfi[qb][ks][0];
        pf.u[1] = pfi[qb][ks][1];
        pf.u[2] = pfi[qb][ks][2];
        pf.u[3] = pfi[qb][ks][3];
#pragma unroll
        for (int n5 = 0; n5 < 5; ++n5)
          oacc[qb][n5] =
              __builtin_amdgcn_mfma_f32_16x16x32_bf16(vfi[n5][ks], pf.v, oacc[qb][n5], 0, 0, 0);
        oacc[qb][5] = __builtin_amdgcn_mfma_f32_16x16x32_bf16(ones.v, pf.v, oacc[qb][5], 0, 0, 0);
      }
    __builtin_amdgcn_s_setprio(0);
  };

  // One pipeline step: QK(t) -> SM(t) -> pack into pfo; V(t) -> vfo; PV(t-1) from pfi/vfi.
  auto STEP = [&](const char* B, unsigned (&pfo)[2][2][4], bf16x8 (&vfo)[5][2],
                  const unsigned (&pfi)[2][2][4], const bf16x8 (&vfi)[5][2], bool dopv) {
    // ---- QK^T: per d-chunk c, load 4 K-frags then 8 MFMAs ----
    f32x4 sacc[2][4] = {};
#pragma unroll
    for (int c = 0; c < 3; ++c) {
      bf16x8 kf[4];
      const char* kc = B + (4 * c + kg) * 1024 + kbase;
#pragma unroll
      for (int nb = 0; nb < 4; ++nb) kf[nb] = *(const bf16x8*)(kc + nb * 256);
      __builtin_amdgcn_s_setprio(1);
#pragma unroll
      for (int qb = 0; qb < 2; ++qb)
#pragma unroll
        for (int nb = 0; nb < 4; ++nb)
          sacc[qb][nb] =
              __builtin_amdgcn_mfma_f32_16x16x32_bf16(kf[nb], qf[qb][c], sacc[qb][nb], 0, 0, 0);
      __builtin_amdgcn_s_setprio(0);
    }
    // ---- V fragments of tile t -> registers (held until next region) ----
#pragma unroll
    for (int n5 = 0; n5 < 5; ++n5)
#pragma unroll
      for (int ks = 0; ks < 2; ++ks) vfo[n5][ks] = *(const bf16x8*)(B + vb_[ks] + n5 * 2048);
    // ---- PV of previous tile (independent of SM below -> co-issues with it) ----
    if (dopv) PV(pfi, vfi);
    // ---- softmax: per-lane local max; cross-lane ONLY when threshold exceeded ----
    float pl[2];
#pragma unroll
    for (int qb = 0; qb < 2; ++qb) {
      float a0 = fmaxf(fmaxf(sacc[qb][0][0], sacc[qb][0][1]), fmaxf(sacc[qb][0][2], sacc[qb][0][3]));
      float a1 = fmaxf(fmaxf(sacc[qb][1][0], sacc[qb][1][1]), fmaxf(sacc[qb][1][2], sacc[qb][1][3]));
      float a2 = fmaxf(fmaxf(sacc[qb][2][0], sacc[qb][2][1]), fmaxf(sacc[qb][2][2], sacc[qb][2][3]));
      float a3 = fmaxf(fmaxf(sacc[qb][3][0], sacc[qb][3][1]), fmaxf(sacc[qb][3][2], sacc[qb][3][3]));
      pl[qb] = fmaxf(fmaxf(a0, a1), fmaxf(a2, a3));
    }
    // fast path: no lane's local max grew past m_run + 8 -> keep m_run, P <= 2^8
    if (!__all((pl[0] - m_run[0] <= 8.0f) & (pl[1] - m_run[1] <= 8.0f))) {
#pragma unroll
      for (int qb = 0; qb < 2; ++qb) {
        float m0 = pl[qb];
        m0 = fmaxf(m0, __shfl_xor(m0, 16, 64));
        m0 = fmaxf(m0, __shfl_xor(m0, 32, 64));
        const float mn = fmaxf(m_run[qb], m0);
        const float fac = __builtin_amdgcn_exp2f(m_run[qb] - mn);
        m_run[qb] = mn;
        // RAW dep on oacc orders this after PV(t-1) above -- correct rescale point
#pragma unroll
        for (int n6 = 0; n6 < 6; ++n6)
#pragma unroll
          for (int r = 0; r < 4; ++r) oacc[qb][n6][r] *= fac;
      }
    }
#pragma unroll
    for (int qb = 0; qb < 2; ++qb)
#pragma unroll
      for (int nb = 0; nb < 4; ++nb)
#pragma unroll
        for (int r = 0; r < 4; ++r)
          sacc[qb][nb][r] = __builtin_amdgcn_exp2f(sacc[qb][nb][r] - m_run[qb]);
    // ---- pack P -> bf16 fragments (k-map matches Vp image) ----
#pragma unroll
    for (int qb = 0; qb < 2; ++qb)
#pragma unroll
      for (int ks = 0; ks < 2; ++ks) {
        pfo[qb][ks][0] = cvtpk(sacc[qb][2 * ks][0], sacc[qb][2 * ks][1]);
        pfo[qb][ks][1] = cvtpk(sacc[qb][2 * ks][2], sacc[qb][2 * ks][3]);
        pfo[qb][ks][2] = cvtpk(sacc[qb][2 * ks + 1][0], sacc[qb][2 * ks + 1][1]);
        pfo[qb][ks][3] = cvtpk(sacc[qb][2 * ks + 1][2], sacc[qb][2 * ks + 1][3]);
      }
  };

  // ---- prologue: fill stages for tiles 0 and 1 ----
  STAGE(0, 0);
  STAGE(1, BUFB);

  // iter 0 (even -> set A), no PV
  STAGE(2, 2 * BUFB);
  if (loww)
    asm volatile("s_waitcnt vmcnt(12)" ::: "memory");
  else
    asm volatile("s_waitcnt vmcnt(10)" ::: "memory");
  __builtin_amdgcn_s_barrier();
  __builtin_amdgcn_sched_barrier(0);
  STEP(smem + 0, pfA, vfA, pfB, vfB, false);
  asm volatile("" ::: "memory");
  __builtin_amdgcn_s_barrier();

  int cur = 1;  // buffer index of the tile being computed
  // iters 1..60 as 30 unrolled pairs (odd -> B, even -> A)
#pragma unroll 1
  for (int tp = 1; tp <= 59; tp += 2) {
    // iter tp (odd): FRONT B, PV from A
    int sb = (cur == 0) ? 2 : (cur - 1);
    STAGE(tp + 2, sb * BUFB);
    if (loww)
      asm volatile("s_waitcnt vmcnt(12)" ::: "memory");
    else
      asm volatile("s_waitcnt vmcnt(10)" ::: "memory");
    __builtin_amdgcn_s_barrier();
    __builtin_amdgcn_sched_barrier(0);
    STEP(smem + cur * BUFB, pfB, vfB, pfA, vfA, true);
    asm volatile("" ::: "memory");
    __builtin_amdgcn_s_barrier();
    cur = (cur == 2) ? 0 : (cur + 1);
    // iter tp+1 (even): FRONT A, PV from B
    sb = (cur == 0) ? 2 : (cur - 1);
    STAGE(tp + 3, sb * BUFB);
    if (loww)
      asm volatile("s_waitcnt vmcnt(12)" ::: "memory");
    else
      asm volatile("s_waitcnt vmcnt(10)" ::: "memory");
    __builtin_amdgcn_s_barrier();
    __builtin_amdgcn_sched_barrier(0);
    STEP(smem + cur * BUFB, pfA, vfA, pfB, vfB, true);
    asm volatile("" ::: "memory");
    __builtin_amdgcn_s_barrier();
    cur = (cur == 2) ? 0 : (cur + 1);
  }
  // iter 61 (odd): stage tile 63, FRONT B, PV from A
  {
    int sb = (cur == 0) ? 2 : (cur - 1);
    STAGE(63, sb * BUFB);
    if (loww)
      asm volatile("s_waitcnt vmcnt(12)" ::: "memory");
    else
      asm volatile("s_waitcnt vmcnt(10)" ::: "memory");
    __builtin_amdgcn_s_barrier();
    __builtin_amdgcn_sched_barrier(0);
    STEP(smem + cur * BUFB, pfB, vfB, pfA, vfA, true);
    asm volatile("" ::: "memory");
    __builtin_amdgcn_s_barrier();
    cur = (cur == 2) ? 0 : (cur + 1);
  }
  // iter 62 (even): one stage (63) still in flight
  if (loww)
    asm volatile("s_waitcnt vmcnt(6)" ::: "memory");
  else
    asm volatile("s_waitcnt vmcnt(5)" ::: "memory");
  __builtin_amdgcn_s_barrier();
  __builtin_amdgcn_sched_barrier(0);
  STEP(smem + cur * BUFB, pfA, vfA, pfB, vfB, true);
  asm volatile("" ::: "memory");
  __builtin_amdgcn_s_barrier();
  cur = (cur == 2) ? 0 : (cur + 1);
  // iter 63 (odd): drain fully
  asm volatile("s_waitcnt vmcnt(0)" ::: "memory");
  __builtin_amdgcn_s_barrier();
  __builtin_amdgcn_sched_barrier(0);
  STEP(smem + cur * BUFB, pfB, vfB, pfA, vfA, true);
  // final PV of tile 63
  PV(pfB, vfB);

  // ---- epilogue: d = n5*16 + kg*4 + r, q = q0 + qb*16 + row16 ----
#pragma unroll
  for (int qb = 0; qb < 2; ++qb) {
    const float rl = 1.0f / oacc[qb][5][0];
    unsigned short* orow = Ob + (size_t)(q0 + qb * 16 + row16) * DIM + h * HD + kg * 4;
#pragma unroll
    for (int n5 = 0; n5 < 5; ++n5) {
      ushort4 o;
      o.x = f2bf(oacc[qb][n5][0] * rl);
      o.y = f2bf(oacc[qb][n5][1] * rl);
      o.z = f2bf(oacc[qb][n5][2] * rl);
      o.w = f2bf(oacc[qb][n5][3] * rl);
      *(ushort4*)(orow + n5 * 16) = o;
    }
  }
}

// ---------------- host ----------------
extern "C" void kernel_launch(void* const* d_in, const int* in_sizes, int n_in, void* d_out,
                              int out_size, void* d_ws, size_t ws_size, hipStream_t stream) {
  (void)in_sizes; (void)n_in; (void)out_size; (void)ws_size;
  const float* hidden = (const float*)d_in[0];
  const float* rope = (const float*)d_in[2];
  const float* qkv_w = (const float*)d_in[3];
  const float* qkv_b = (const float*)d_in[4];
  const float* proj_w = (const float*)d_in[5];
  const float* proj_b = (const float*)d_in[6];

  char* p = (char*)d_ws;
  unsigned short* Xb = (unsigned short*)p;       p += (size_t)SEQ * DIM * 2;
  unsigned short* Wq = (unsigned short*)p;       p += (size_t)TDIM * DIM * 2;
  unsigned short* Wp = (unsigned short*)p;       p += (size_t)DIM * DIM * 2;
  float* ct = (float*)p;                         p += (size_t)SEQ * HD * 4;
  float* st = (float*)p;                         p += (size_t)SEQ * HD * 4;
  unsigned short* Y = (unsigned short*)p;        p += (size_t)SEQ * TDIM * 2;
  unsigned short* Qr = (unsigned short*)p;       p += (size_t)NH * SEQ * HQ * 2;
  unsigned short* Kr = (unsigned short*)p;       p += (size_t)NH * SEQ * HQ * 2;
  unsigned short* Vp = (unsigned short*)p;       p += (size_t)NH * HD * SEQ * 2;
  unsigned short* Ob = (unsigned short*)p;       p += (size_t)SEQ * DIM * 2;

  prep<<<2048, 256, 0, stream>>>(hidden, qkv_w, proj_w, rope, Xb, Wq, Wp, ct, st);
  // QKV GEMM: 256^2 tile, 4-phase interleave, grid 240 (16 x 15)
  gemmq<<<240, 512, 0, stream>>>(Xb, Wq, qkv_b, Y);
  rope_qk2<<<SEQ, 256, 0, stream>>>(Y, ct, st, Qr, Kr);
  vtrans3<<<dim3(NH, SEQ / 64), 256, 0, stream>>>(Y, Vp);
  attn8<<<512, 256, 0, stream>>>(Qr, Kr, Vp, Ob);
  gemm_bt<1><<<dim3(DIM / 128, SEQ / 128), 256, 0, stream>>>(Ob, Wp, proj_b, d_out, SEQ, DIM, DIM);
}

// Round 12
// 207.231 us; speedup vs baseline: 1.1849x; 1.0467x over previous
//
#include <hip/hip_runtime.h>

#define SEQ 4096
#define DIM 1280
#define NH 16
#define HD 80
#define HQ 96
#define TDIM 3840

// softmax scale (1/sqrt(80)) * log2(e), folded into Q at repack
#define QSC 0.16129842980505168f

typedef __bf16 bf16x8 __attribute__((ext_vector_type(8)));
typedef __bf16 bf16x4 __attribute__((ext_vector_type(4)));
typedef float f32x4 __attribute__((ext_vector_type(4)));

__device__ __forceinline__ unsigned short f2bf(float f) {
  unsigned int u = __builtin_bit_cast(unsigned int, f);
  u += 0x7FFF + ((u >> 16) & 1);
  return (unsigned short)(u >> 16);
}
__device__ __forceinline__ float bf2f(unsigned short b) {
  unsigned int u = ((unsigned int)b) << 16;
  return __builtin_bit_cast(float, u);
}
__device__ __forceinline__ unsigned int cvtpk(float a, float b) {
  unsigned int r;
  asm("v_cvt_pk_bf16_f32 %0, %1, %2" : "=v"(r) : "v"(a), "v"(b));
  return r;
}

__device__ __forceinline__ void gload_lds16(const void* g, void* l) {
  __builtin_amdgcn_global_load_lds(
      (const __attribute__((address_space(1))) unsigned int*)g,
      (__attribute__((address_space(3))) unsigned int*)l, 16, 0, 0);
}

// ---------------- fused prep: fp32->bf16 x3 + cos/sin table ----------------
__global__ __launch_bounds__(256) void prep(const float* __restrict__ X,
                                            const float* __restrict__ Wq,
                                            const float* __restrict__ Wp,
                                            const float* __restrict__ rope,
                                            unsigned short* __restrict__ Xb,
                                            unsigned short* __restrict__ Wqb,
                                            unsigned short* __restrict__ Wpb,
                                            float* __restrict__ ct, float* __restrict__ st) {
  constexpr int N0 = SEQ * DIM / 4;
  constexpr int N1 = TDIM * DIM / 4;
  constexpr int N2 = DIM * DIM / 4;
  constexpr int N3 = SEQ * HD / 4;
  const int stride = gridDim.x * 256;
  for (int i = blockIdx.x * 256 + threadIdx.x; i < N0 + N1 + N2 + N3; i += stride) {
    if (i < N0 + N1 + N2) {
      const float4* src;
      unsigned short* dst;
      int j;
      if (i < N0) {
        src = (const float4*)X; dst = Xb; j = i;
      } else if (i < N0 + N1) {
        src = (const float4*)Wq; dst = Wqb; j = i - N0;
      } else {
        src = (const float4*)Wp; dst = Wpb; j = i - N0 - N1;
      }
      float4 f = src[j];
      ushort4 o;
      o.x = f2bf(f.x); o.y = f2bf(f.y); o.z = f2bf(f.z); o.w = f2bf(f.w);
      ((ushort4*)dst)[j] = o;
    } else {
      const int j = i - N0 - N1 - N2;
      float4 v = ((const float4*)rope)[j];
      float4 c, s;
      c.x = cosf(v.x); c.y = cosf(v.y); c.z = cosf(v.z); c.w = cosf(v.w);
      s.x = sinf(v.x); s.y = sinf(v.y); s.z = sinf(v.z); s.w = sinf(v.w);
      ((float4*)ct)[j] = c;
      ((float4*)st)[j] = s;
    }
  }
}

// ---------------- QKV GEMM: 256x256 tile, BK=64, 4-phase interleave ----------------
__global__ __launch_bounds__(512, 1) void gemmq(const unsigned short* __restrict__ A,
                                                const unsigned short* __restrict__ B,
                                                const float* __restrict__ bias,
                                                unsigned short* __restrict__ Cout) {
  __shared__ char smem[131072];
  const int tid = threadIdx.x;
  const int l = tid & 63, w = tid >> 6;
  const int row16 = l & 15, kg = l >> 4;
  const int wr = w >> 2, wc = w & 3;

  const int bid = blockIdx.x;
  const int swz = (bid & 7) * 30 + (bid >> 3);
  const int ny = swz / 15, nx = swz - ny * 15;
  const int brow = ny * 256, bcol = nx * 256;

  constexpr int Kb = 2560;
  const char* Ag = (const char*)A + (size_t)brow * Kb;
  const char* Bg = (const char*)B + (size_t)bcol * Kb;

  unsigned soff[4], sdst[4];
#pragma unroll
  for (int i = 0; i < 4; ++i) {
    const int u = ((w * 4 + i) << 6) + l;
    const int row = u >> 3;
    const int cg = (u & 7) ^ (row & 7);
    soff[i] = row * Kb + cg * 16;
    sdst[i] = u * 16;
  }
  auto SGA = [&](int kt, int b, int i) {
    gload_lds16(Ag + kt * 128 + soff[i], smem + b * 65536 + sdst[i]);
  };
  auto SGB = [&](int kt, int b, int i) {
    gload_lds16(Bg + kt * 128 + soff[i], smem + b * 65536 + 32768 + sdst[i]);
  };

  f32x4 acc[8][4] = {};
  const int arow = (wr * 128 + row16) * 128;
  const int brow_ = (wc * 64 + row16) * 128;
  int cswz[2];
#pragma unroll
  for (int ks = 0; ks < 2; ++ks) cswz[ks] = (ks * 64 + kg * 16) ^ ((row16 & 7) << 4);

#pragma unroll
  for (int i = 0; i < 4; ++i) SGA(0, 0, i);
#pragma unroll
  for (int i = 0; i < 4; ++i) SGB(0, 0, i);

  constexpr int NKT = 20;
#pragma unroll 1
  for (int t = 0; t < NKT; ++t) {
    const int cb = t & 1, nb2 = cb ^ 1;
    const bool more = (t + 1 < NKT);
    if (more) {
      SGA(t + 1, nb2, 0);
      SGB(t + 1, nb2, 0);
      asm volatile("s_waitcnt vmcnt(2)" ::: "memory");
    } else {
      asm volatile("s_waitcnt vmcnt(0)" ::: "memory");
    }
    __builtin_amdgcn_s_barrier();
    __builtin_amdgcn_sched_barrier(0);
    const char* Ab = smem + cb * 65536;
    const char* Bb = Ab + 32768;

    bf16x8 bf0[4], af[4];
#pragma unroll
    for (int ni = 0; ni < 4; ++ni) bf0[ni] = *(const bf16x8*)(Bb + brow_ + ni * 2048 + cswz[0]);
#pragma unroll
    for (int m4 = 0; m4 < 4; ++m4) af[m4] = *(const bf16x8*)(Ab + arow + m4 * 2048 + cswz[0]);
    asm volatile("s_waitcnt lgkmcnt(0)" ::: "memory");
    __builtin_amdgcn_sched_barrier(0);
    __builtin_amdgcn_s_setprio(1);
#pragma unroll
    for (int m4 = 0; m4 < 4; ++m4)
#pragma unroll
      for (int ni = 0; ni < 4; ++ni)
        acc[m4][ni] = __builtin_amdgcn_mfma_f32_16x16x32_bf16(af[m4], bf0[ni], acc[m4][ni], 0, 0, 0);
    __builtin_amdgcn_s_setprio(0);
    __builtin_amdgcn_s_barrier();
    if (more) { SGA(t + 1, nb2, 1); SGB(t + 1, nb2, 1); }
#pragma unroll
    for (int m4 = 0; m4 < 4; ++m4) af[m4] = *(const bf16x8*)(Ab + arow + (m4 + 4) * 2048 + cswz[0]);
    asm volatile("s_waitcnt lgkmcnt(0)" ::: "memory");
    __builtin_amdgcn_sched_barrier(0);
    __builtin_amdgcn_s_setprio(1);
#pragma unroll
    for (int m4 = 0; m4 < 4; ++m4)
#pragma unroll
      for (int ni = 0; ni < 4; ++ni)
        acc[m4 + 4][ni] =
            __builtin_amdgcn_mfma_f32_16x16x32_bf16(af[m4], bf0[ni], acc[m4 + 4][ni], 0, 0, 0);
    __builtin_amdgcn_s_setprio(0);
    __builtin_amdgcn_s_barrier();
    if (more) { SGA(t + 1, nb2, 2); SGB(t + 1, nb2, 2); }
#pragma unroll
    for (int ni = 0; ni < 4; ++ni) bf0[ni] = *(const bf16x8*)(Bb + brow_ + ni * 2048 + cswz[1]);
#pragma unroll
    for (int m4 = 0; m4 < 4; ++m4) af[m4] = *(const bf16x8*)(Ab + arow + m4 * 2048 + cswz[1]);
    asm volatile("s_waitcnt lgkmcnt(0)" ::: "memory");
    __builtin_amdgcn_sched_barrier(0);
    __builtin_amdgcn_s_setprio(1);
#pragma unroll
    for (int m4 = 0; m4 < 4; ++m4)
#pragma unroll
      for (int ni = 0; ni < 4; ++ni)
        acc[m4][ni] = __builtin_amdgcn_mfma_f32_16x16x32_bf16(af[m4], bf0[ni], acc[m4][ni], 0, 0, 0);
    __builtin_amdgcn_s_setprio(0);
    __builtin_amdgcn_s_barrier();
    if (more) { SGA(t + 1, nb2, 3); SGB(t + 1, nb2, 3); }
#pragma unroll
    for (int m4 = 0; m4 < 4; ++m4) af[m4] = *(const bf16x8*)(Ab + arow + (m4 + 4) * 2048 + cswz[1]);
    asm volatile("s_waitcnt lgkmcnt(0)" ::: "memory");
    __builtin_amdgcn_sched_barrier(0);
    __builtin_amdgcn_s_setprio(1);
#pragma unroll
    for (int m4 = 0; m4 < 4; ++m4)
#pragma unroll
      for (int ni = 0; ni < 4; ++ni)
        acc[m4 + 4][ni] =
            __builtin_amdgcn_mfma_f32_16x16x32_bf16(af[m4], bf0[ni], acc[m4 + 4][ni], 0, 0, 0);
    __builtin_amdgcn_s_setprio(0);
    __builtin_amdgcn_s_barrier();
  }

#pragma unroll
  for (int ni = 0; ni < 4; ++ni) {
    const int col = bcol + wc * 64 + ni * 16 + row16;
    const float bv = bias[col];
#pragma unroll
    for (int mi = 0; mi < 8; ++mi) {
      const int row = brow + wr * 128 + mi * 16 + kg * 4;
#pragma unroll
      for (int r = 0; r < 4; ++r)
        Cout[(size_t)(row + r) * TDIM + col] = f2bf(acc[mi][ni][r] + bv);
    }
  }
}

// ---------------- out-proj GEMM: 128x256 tile, BK=64, 2-phase, fp32 out ----------------
// C(4096x1280) = Ob(4096x1280) @ Wp(1280x1280)^T + bias. grid 160 (32 x 5).
__global__ __launch_bounds__(512, 1) void gemmp(const unsigned short* __restrict__ A,
                                                const unsigned short* __restrict__ B,
                                                const float* __restrict__ bias,
                                                float* __restrict__ Cout) {
  __shared__ char smem[98304];  // A: 2 x 16KB at 0; B: 2 x 32KB at 32768
  const int tid = threadIdx.x;
  const int l = tid & 63, w = tid >> 6;
  const int row16 = l & 15, kg = l >> 4;
  const int wr = w >> 2, wc = w & 3;

  const int bid = blockIdx.x;
  const int swz = (bid & 7) * 20 + (bid >> 3);
  const int ny = swz / 5, nx = swz - ny * 5;
  const int brow = ny * 128, bcol = nx * 256;

  constexpr int Kb = 2560;
  const char* Ag = (const char*)A + (size_t)brow * Kb;
  const char* Bg = (const char*)B + (size_t)bcol * Kb;

  // 3072 units: jj<2 -> A (1024 units), jj>=2 -> B (2048 units)
  unsigned soff[6], sdst[6];
#pragma unroll
  for (int jj = 0; jj < 6; ++jj) {
    const int u = tid + 512 * jj;
    const int v = (u < 1024) ? u : (u - 1024);
    const int row = v >> 3;
    const int cg = (v & 7) ^ (row & 7);
    soff[jj] = row * Kb + cg * 16;
    sdst[jj] = v * 16;
  }
  auto SG = [&](int kt, int b, int part) {
#pragma unroll
    for (int jj3 = 0; jj3 < 3; ++jj3) {
      const int jj = part * 3 + jj3;
      const bool isa = (jj < 2);
      gload_lds16((isa ? Ag : Bg) + kt * 128 + soff[jj],
                  smem + (isa ? b * 16384 : 32768 + b * 32768) + sdst[jj]);
    }
  };

  f32x4 acc[4][4] = {};
  const int arow = (wr * 64 + row16) * 128;
  const int brow_ = (wc * 64 + row16) * 128;
  int cswz[2];
#pragma unroll
  for (int ks = 0; ks < 2; ++ks) cswz[ks] = (ks * 64 + kg * 16) ^ ((row16 & 7) << 4);

  SG(0, 0, 0);
  SG(0, 0, 1);

  constexpr int NKT = 20;
#pragma unroll 1
  for (int t = 0; t < NKT; ++t) {
    const int cb = t & 1, nb2 = cb ^ 1;
    const bool more = (t + 1 < NKT);
    if (more) {
      SG(t + 1, nb2, 0);
      asm volatile("s_waitcnt vmcnt(3)" ::: "memory");
    } else {
      asm volatile("s_waitcnt vmcnt(0)" ::: "memory");
    }
    __builtin_amdgcn_s_barrier();
    __builtin_amdgcn_sched_barrier(0);
    const char* Ab = smem + cb * 16384;
    const char* Bb = smem + 32768 + cb * 32768;

    bf16x8 bf0[4], af[4];
    // phase 0: ks = 0
#pragma unroll
    for (int ni = 0; ni < 4; ++ni) bf0[ni] = *(const bf16x8*)(Bb + brow_ + ni * 2048 + cswz[0]);
#pragma unroll
    for (int mi = 0; mi < 4; ++mi) af[mi] = *(const bf16x8*)(Ab + arow + mi * 2048 + cswz[0]);
    asm volatile("s_waitcnt lgkmcnt(0)" ::: "memory");
    __builtin_amdgcn_sched_barrier(0);
    __builtin_amdgcn_s_setprio(1);
#pragma unroll
    for (int mi = 0; mi < 4; ++mi)
#pragma unroll
      for (int ni = 0; ni < 4; ++ni)
        acc[mi][ni] = __builtin_amdgcn_mfma_f32_16x16x32_bf16(af[mi], bf0[ni], acc[mi][ni], 0, 0, 0);
    __builtin_amdgcn_s_setprio(0);
    __builtin_amdgcn_s_barrier();
    // phase 1: ks = 1
    if (more) SG(t + 1, nb2, 1);
#pragma unroll
    for (int ni = 0; ni < 4; ++ni) bf0[ni] = *(const bf16x8*)(Bb + brow_ + ni * 2048 + cswz[1]);
#pragma unroll
    for (int mi = 0; mi < 4; ++mi) af[mi] = *(const bf16x8*)(Ab + arow + mi * 2048 + cswz[1]);
    asm volatile("s_waitcnt lgkmcnt(0)" ::: "memory");
    __builtin_amdgcn_sched_barrier(0);
    __builtin_amdgcn_s_setprio(1);
#pragma unroll
    for (int mi = 0; mi < 4; ++mi)
#pragma unroll
      for (int ni = 0; ni < 4; ++ni)
        acc[mi][ni] = __builtin_amdgcn_mfma_f32_16x16x32_bf16(af[mi], bf0[ni], acc[mi][ni], 0, 0, 0);
    __builtin_amdgcn_s_setprio(0);
    __builtin_amdgcn_s_barrier();
  }

#pragma unroll
  for (int ni = 0; ni < 4; ++ni) {
    const int col = bcol + wc * 64 + ni * 16 + row16;
    const float bv = bias[col];
#pragma unroll
    for (int mi = 0; mi < 4; ++mi) {
      const int row = brow + wr * 64 + mi * 16 + kg * 4;
#pragma unroll
      for (int r = 0; r < 4; ++r)
        Cout[(size_t)(row + r) * DIM + col] = acc[mi][ni][r] + bv;
    }
  }
}

// ---------------- RoPE + repack Q,K -> [h][s][96]; Q pre-scaled ----------------
__global__ __launch_bounds__(256) void rope_qk2(const unsigned short* __restrict__ Y,
                                                const float* __restrict__ ct,
                                                const float* __restrict__ st,
                                                unsigned short* __restrict__ Qr,
                                                unsigned short* __restrict__ Kr) {
  const int s = blockIdx.x, tid = threadIdx.x;
  const unsigned short* yq = Y + (size_t)s * TDIM;
  const unsigned short* yk = yq + DIM;
  for (int i = tid; i < 640; i += 256) {
    const int h = i / 40, j = i - h * 40;
    const float c0 = ct[s * HD + j], c1 = ct[s * HD + j + 40];
    const float s0 = st[s * HD + j], s1 = st[s * HD + j + 40];
    const float q0 = bf2f(yq[h * HD + j]), q1 = bf2f(yq[h * HD + j + 40]);
    const float k0 = bf2f(yk[h * HD + j]), k1 = bf2f(yk[h * HD + j + 40]);
    const size_t o = ((size_t)h * SEQ + s) * HQ;
    Qr[o + j] = f2bf((q0 * c0 - q1 * s0) * QSC);
    Qr[o + j + 40] = f2bf((q1 * c1 + q0 * s1) * QSC);
    Kr[o + j] = f2bf(k0 * c0 - k1 * s0);
    Kr[o + j + 40] = f2bf(k1 * c1 + k0 * s1);
  }
  {  // zero pad d = 80..95 for all 16 heads
    const int h = tid >> 4, dp = 80 + (tid & 15);
    const size_t o = ((size_t)h * SEQ + s) * HQ + dp;
    Qr[o] = 0;
    Kr[o] = 0;
  }
}

// ---------------- V transpose -> permuted image Vp[h][d][4096] ----------------
__global__ __launch_bounds__(256) void vtrans3(const unsigned short* __restrict__ Y,
                                               unsigned short* __restrict__ Vp) {
  __shared__ unsigned short tile[64][128];
  const int h = blockIdx.x, s0 = blockIdx.y * 64, tid = threadIdx.x;
  const unsigned short* src = Y + 2 * DIM + h * HD;
  for (int u = tid; u < 640; u += 256) {
    const int s = u / 10, j = u - s * 10;
    uint4 v = *(const uint4*)(src + (size_t)(s0 + s) * TDIM + j * 8);
    *(uint4*)&tile[s][(j ^ ((s >> 3) & 7)) << 3] = v;
  }
  __syncthreads();
  for (int u = tid; u < 640; u += 256) {
    const int d = u >> 3, g = u & 7;
    const int gl = g ^ (d & 7);
    const int base_s = (gl & 1) * 32 + (gl >> 1) * 4;
    unsigned short tmp[8];
#pragma unroll
    for (int sub = 0; sub < 8; ++sub) {
      const int s = base_s + (sub >> 2) * 16 + (sub & 3);
      tmp[sub] = tile[s][(((d >> 3) ^ ((s >> 3) & 7)) << 3) + (d & 7)];
    }
    *(uint4*)(Vp + (size_t)(h * HD + d) * SEQ + s0 + g * 8) = *(uint4*)tmp;
  }
}

// ---------------- Flash attention v8: ring-3 counted vmcnt + 1-deep PV pipeline ----
__global__ __launch_bounds__(256, 2) void attn8(const unsigned short* __restrict__ Qr,
                                                const unsigned short* __restrict__ Kr,
                                                const unsigned short* __restrict__ Vp,
                                                unsigned short* __restrict__ Ob) {
  constexpr int KBYT = 12288;
  constexpr int VBYT = 10240;
  constexpr int BUFB = KBYT + VBYT;  // 22528
  constexpr int NT = SEQ / 64;       // 64 tiles
  __shared__ char smem[3 * BUFB];

  const int tid = threadIdx.x;
  const int l = tid & 63, w = tid >> 6;
  const int row16 = l & 15, kg = l >> 4;
  const int bid = blockIdx.x;
  const int h = bid & 15;
  const int q0 = (bid >> 4) * 128 + w * 32;
  const size_t hs = (size_t)h * SEQ;
  const bool loww = (w < 2);

  const unsigned short* Qh = Qr + hs * HQ;
  const char* Kh = (const char*)(Kr + hs * HQ);
  const char* Vh = (const char*)(Vp + (size_t)h * HD * SEQ);

  // staging: 1408 16B-units (768 K + 640 V); unit u = tid + 256*i
  unsigned soff[6], sdst[6];
  bool isk[6];
  const int cnt = (tid < 128) ? 6 : 5;
#pragma unroll
  for (int i = 0; i < 6; ++i) {
    const int u = tid + 256 * i;
    if (u < 768) {
      soff[i] = (u & 63) * 192 + (u >> 6) * 16;
      isk[i] = true;
    } else {
      const int v = u - 768;
      soff[i] = (v >> 3) * 8192 + (v & 7) * 16;
      isk[i] = false;
    }
    sdst[i] = u << 4;
  }
  auto STAGE = [&](int t, int bb) {
    const char* kb = Kh + (size_t)t * 12288;
    const char* vb = Vh + (size_t)t * 128;
#pragma unroll
    for (int i = 0; i < 6; ++i)
      if (i < cnt) gload_lds16((isk[i] ? kb : vb) + soff[i], smem + bb + sdst[i]);
  };

  // LDS read bases (tile-invariant)
  const int kbase = row16 * 16;  // + (4c+kg)*1024 + nb*256
  int vb_[2];
#pragma unroll
  for (int ks = 0; ks < 2; ++ks)
    vb_[ks] = KBYT + row16 * 128 + ((((kg << 1) | ks) ^ (row16 & 7)) << 4);  // + n5*2048

  // Q fragments (B-operand of swapped QK^T): q = q0 + qb*16 + row16
  bf16x8 qf[2][3];
#pragma unroll
  for (int qb = 0; qb < 2; ++qb)
#pragma unroll
    for (int c = 0; c < 3; ++c)
      qf[qb][c] = *(const bf16x8*)&Qh[(size_t)(q0 + qb * 16 + row16) * HQ + c * 32 + kg * 8];
  // Force the compiler's vmcnt wait for qf HERE (pre-pipeline), not inside the loop.
  asm volatile("" ::"v"(qf[0][0]), "v"(qf[0][1]), "v"(qf[0][2]));
  asm volatile("" ::"v"(qf[1][0]), "v"(qf[1][1]), "v"(qf[1][2]));

  union { bf16x8 v; unsigned int u[4]; } ones;
  ones.u[0] = ones.u[1] = ones.u[2] = ones.u[3] = 0x3F803F80u;

  float m_run[2] = {-3.0e38f, -3.0e38f};
  f32x4 oacc[2][6] = {};  // [qb][d-block 0..4, 5 = row-sum l]

  // pipeline state: packed P and V fragments of the previous tile (A/B sets)
  unsigned pfA[2][2][4], pfB[2][2][4];
  bf16x8 vfA[5][2], vfB[5][2];

  // PV of a previous tile: pure register MFMA (no LDS) -> can overlap SM of cur tile
  auto PV = [&](const unsigned (&pfi)[2][2][4], const bf16x8 (&vfi)[5][2]) {
    __builtin_amdgcn_s_setprio(1);
#pragma unroll
    for (int qb = 0; qb < 2; ++qb)
#pragma unroll
      for (int ks = 0; ks < 2; ++ks) {
        union { bf16x8 v; unsigned int u[4]; } pf;
        pf.u[0] = pfi[qb][ks][0];
        pf.u[1] = pfi[qb][ks][1];
        pf.u[2] = pfi[qb][ks][2];
        pf.u[3] = pfi[qb][ks][3];
#pragma unroll
        for (int n5 = 0; n5 < 5; ++n5)
          oacc[qb][n5] =
              __builtin_amdgcn_mfma_f32_16x16x32_bf16(vfi[n5][ks], pf.v, oacc[qb][n5], 0, 0, 0);
        oacc[qb][5] = __builtin_amdgcn_mfma_f32_16x16x32_bf16(ones.v, pf.v, oacc[qb][5], 0, 0, 0);
      }
    __builtin_amdgcn_s_setprio(0);
  };

  // One pipeline step: QK(t) -> SM(t) -> pack into pfo; V(t) -> vfo; PV(t-1) from pfi/vfi.
  auto STEP = [&](const char* B, unsigned (&pfo)[2][2][4], bf16x8 (&vfo)[5][2],
                  const unsigned (&pfi)[2][2][4], const bf16x8 (&vfi)[5][2], bool dopv) {
    // ---- QK^T: per d-chunk c, load 4 K-frags then 8 MFMAs ----
    f32x4 sacc[2][4] = {};
#pragma unroll
    for (int c = 0; c < 3; ++c) {
      bf16x8 kf[4];
      const char* kc = B + (4 * c + kg) * 1024 + kbase;
#pragma unroll
      for (int nb = 0; nb < 4; ++nb) kf[nb] = *(const bf16x8*)(kc + nb * 256);
      __builtin_amdgcn_s_setprio(1);
#pragma unroll
      for (int qb = 0; qb < 2; ++qb)
#pragma unroll
        for (int nb = 0; nb < 4; ++nb)
          sacc[qb][nb] =
              __builtin_amdgcn_mfma_f32_16x16x32_bf16(kf[nb], qf[qb][c], sacc[qb][nb], 0, 0, 0);
      __builtin_amdgcn_s_setprio(0);
    }
    // ---- V fragments of tile t -> registers (held until next region) ----
#pragma unroll
    for (int n5 = 0; n5 < 5; ++n5)
#pragma unroll
      for (int ks = 0; ks < 2; ++ks) vfo[n5][ks] = *(const bf16x8*)(B + vb_[ks] + n5 * 2048);
    // ---- PV of previous tile (independent of SM below -> co-issues with it) ----
    if (dopv) PV(pfi, vfi);
    // ---- softmax: per-lane local max; cross-lane ONLY when threshold exceeded ----
    float pl[2];
#pragma unroll
    for (int qb = 0; qb < 2; ++qb) {
      float a0 = fmaxf(fmaxf(sacc[qb][0][0], sacc[qb][0][1]), fmaxf(sacc[qb][0][2], sacc[qb][0][3]));
      float a1 = fmaxf(fmaxf(sacc[qb][1][0], sacc[qb][1][1]), fmaxf(sacc[qb][1][2], sacc[qb][1][3]));
      float a2 = fmaxf(fmaxf(sacc[qb][2][0], sacc[qb][2][1]), fmaxf(sacc[qb][2][2], sacc[qb][2][3]));
      float a3 = fmaxf(fmaxf(sacc[qb][3][0], sacc[qb][3][1]), fmaxf(sacc[qb][3][2], sacc[qb][3][3]));
      pl[qb] = fmaxf(fmaxf(a0, a1), fmaxf(a2, a3));
    }
    // fast path: no lane's local max grew past m_run + 8 -> keep m_run, P <= 2^8
    if (!__all((pl[0] - m_run[0] <= 8.0f) & (pl[1] - m_run[1] <= 8.0f))) {
#pragma unroll
      for (int qb = 0; qb < 2; ++qb) {
        float m0 = pl[qb];
        m0 = fmaxf(m0, __shfl_xor(m0, 16, 64));
        m0 = fmaxf(m0, __shfl_xor(m0, 32, 64));
        const float mn = fmaxf(m_run[qb], m0);
        const float fac = __builtin_amdgcn_exp2f(m_run[qb] - mn);
        m_run[qb] = mn;
        // RAW dep on oacc orders this after PV(t-1) above -- correct rescale point
#pragma unroll
        for (int n6 = 0; n6 < 6; ++n6)
#pragma unroll
          for (int r = 0; r < 4; ++r) oacc[qb][n6][r] *= fac;
      }
    }
#pragma unroll
    for (int qb = 0; qb < 2; ++qb)
#pragma unroll
      for (int nb = 0; nb < 4; ++nb)
#pragma unroll
        for (int r = 0; r < 4; ++r)
          sacc[qb][nb][r] = __builtin_amdgcn_exp2f(sacc[qb][nb][r] - m_run[qb]);
    // ---- pack P -> bf16 fragments (k-map matches Vp image) ----
#pragma unroll
    for (int qb = 0; qb < 2; ++qb)
#pragma unroll
      for (int ks = 0; ks < 2; ++ks) {
        pfo[qb][ks][0] = cvtpk(sacc[qb][2 * ks][0], sacc[qb][2 * ks][1]);
        pfo[qb][ks][1] = cvtpk(sacc[qb][2 * ks][2], sacc[qb][2 * ks][3]);
        pfo[qb][ks][2] = cvtpk(sacc[qb][2 * ks + 1][0], sacc[qb][2 * ks + 1][1]);
        pfo[qb][ks][3] = cvtpk(sacc[qb][2 * ks + 1][2], sacc[qb][2 * ks + 1][3]);
      }
  };

  // ---- prologue: fill stages for tiles 0 and 1 ----
  STAGE(0, 0);
  STAGE(1, BUFB);

  // iter 0 (even -> set A), no PV
  STAGE(2, 2 * BUFB);
  if (loww)
    asm volatile("s_waitcnt vmcnt(12)" ::: "memory");
  else
    asm volatile("s_waitcnt vmcnt(10)" ::: "memory");
  __builtin_amdgcn_s_barrier();
  __builtin_amdgcn_sched_barrier(0);
  STEP(smem + 0, pfA, vfA, pfB, vfB, false);
  asm volatile("" ::: "memory");
  __builtin_amdgcn_s_barrier();

  int cur = 1;  // buffer index of the tile being computed
  // iters 1..60 as 30 unrolled pairs (odd -> B, even -> A)
#pragma unroll 1
  for (int tp = 1; tp <= 59; tp += 2) {
    // iter tp (odd): FRONT B, PV from A
    int sb = (cur == 0) ? 2 : (cur - 1);
    STAGE(tp + 2, sb * BUFB);
    if (loww)
      asm volatile("s_waitcnt vmcnt(12)" ::: "memory");
    else
      asm volatile("s_waitcnt vmcnt(10)" ::: "memory");
    __builtin_amdgcn_s_barrier();
    __builtin_amdgcn_sched_barrier(0);
    STEP(smem + cur * BUFB, pfB, vfB, pfA, vfA, true);
    asm volatile("" ::: "memory");
    __builtin_amdgcn_s_barrier();
    cur = (cur == 2) ? 0 : (cur + 1);
    // iter tp+1 (even): FRONT A, PV from B
    sb = (cur == 0) ? 2 : (cur - 1);
    STAGE(tp + 3, sb * BUFB);
    if (loww)
      asm volatile("s_waitcnt vmcnt(12)" ::: "memory");
    else
      asm volatile("s_waitcnt vmcnt(10)" ::: "memory");
    __builtin_amdgcn_s_barrier();
    __builtin_amdgcn_sched_barrier(0);
    STEP(smem + cur * BUFB, pfA, vfA, pfB, vfB, true);
    asm volatile("" ::: "memory");
    __builtin_amdgcn_s_barrier();
    cur = (cur == 2) ? 0 : (cur + 1);
  }
  // iter 61 (odd): stage tile 63, FRONT B, PV from A
  {
    int sb = (cur == 0) ? 2 : (cur - 1);
    STAGE(63, sb * BUFB);
    if (loww)
      asm volatile("s_waitcnt vmcnt(12)" ::: "memory");
    else
      asm volatile("s_waitcnt vmcnt(10)" ::: "memory");
    __builtin_amdgcn_s_barrier();
    __builtin_amdgcn_sched_barrier(0);
    STEP(smem + cur * BUFB, pfB, vfB, pfA, vfA, true);
    asm volatile("" ::: "memory");
    __builtin_amdgcn_s_barrier();
    cur = (cur == 2) ? 0 : (cur + 1);
  }
  // iter 62 (even): one stage (63) still in flight
  if (loww)
    asm volatile("s_waitcnt vmcnt(6)" ::: "memory");
  else
    asm volatile("s_waitcnt vmcnt(5)" ::: "memory");
  __builtin_amdgcn_s_barrier();
  __builtin_amdgcn_sched_barrier(0);
  STEP(smem + cur * BUFB, pfA, vfA, pfB, vfB, true);
  asm volatile("" ::: "memory");
  __builtin_amdgcn_s_barrier();
  cur = (cur == 2) ? 0 : (cur + 1);
  // iter 63 (odd): drain fully
  asm volatile("s_waitcnt vmcnt(0)" ::: "memory");
  __builtin_amdgcn_s_barrier();
  __builtin_amdgcn_sched_barrier(0);
  STEP(smem + cur * BUFB, pfB, vfB, pfA, vfA, true);
  // final PV of tile 63
  PV(pfB, vfB);

  // ---- epilogue: d = n5*16 + kg*4 + r, q = q0 + qb*16 + row16 ----
#pragma unroll
  for (int qb = 0; qb < 2; ++qb) {
    const float rl = 1.0f / oacc[qb][5][0];
    unsigned short* orow = Ob + (size_t)(q0 + qb * 16 + row16) * DIM + h * HD + kg * 4;
#pragma unroll
    for (int n5 = 0; n5 < 5; ++n5) {
      ushort4 o;
      o.x = f2bf(oacc[qb][n5][0] * rl);
      o.y = f2bf(oacc[qb][n5][1] * rl);
      o.z = f2bf(oacc[qb][n5][2] * rl);
      o.w = f2bf(oacc[qb][n5][3] * rl);
      *(ushort4*)(orow + n5 * 16) = o;
    }
  }
}

// ---------------- host ----------------
extern "C" void kernel_launch(void* const* d_in, const int* in_sizes, int n_in, void* d_out,
                              int out_size, void* d_ws, size_t ws_size, hipStream_t stream) {
  (void)in_sizes; (void)n_in; (void)out_size; (void)ws_size;
  const float* hidden = (const float*)d_in[0];
  const float* rope = (const float*)d_in[2];
  const float* qkv_w = (const float*)d_in[3];
  const float* qkv_b = (const float*)d_in[4];
  const float* proj_w = (const float*)d_in[5];
  const float* proj_b = (const float*)d_in[6];

  char* p = (char*)d_ws;
  unsigned short* Xb = (unsigned short*)p;       p += (size_t)SEQ * DIM * 2;
  unsigned short* Wq = (unsigned short*)p;       p += (size_t)TDIM * DIM * 2;
  unsigned short* Wp = (unsigned short*)p;       p += (size_t)DIM * DIM * 2;
  float* ct = (float*)p;                         p += (size_t)SEQ * HD * 4;
  float* st = (float*)p;                         p += (size_t)SEQ * HD * 4;
  unsigned short* Y = (unsigned short*)p;        p += (size_t)SEQ * TDIM * 2;
  unsigned short* Qr = (unsigned short*)p;       p += (size_t)NH * SEQ * HQ * 2;
  unsigned short* Kr = (unsigned short*)p;       p += (size_t)NH * SEQ * HQ * 2;
  unsigned short* Vp = (unsigned short*)p;       p += (size_t)NH * HD * SEQ * 2;
  unsigned short* Ob = (unsigned short*)p;       p += (size_t)SEQ * DIM * 2;

  prep<<<2048, 256, 0, stream>>>(hidden, qkv_w, proj_w, rope, Xb, Wq, Wp, ct, st);
  gemmq<<<240, 512, 0, stream>>>(Xb, Wq, qkv_b, Y);
  rope_qk2<<<SEQ, 256, 0, stream>>>(Y, ct, st, Qr, Kr);
  vtrans3<<<dim3(NH, SEQ / 64), 256, 0, stream>>>(Y, Vp);
  attn8<<<512, 256, 0, stream>>>(Qr, Kr, Vp, Ob);
  gemmp<<<160, 512, 0, stream>>>(Ob, Wp, proj_b, (float*)d_out);
}

// Round 14
// 204.028 us; speedup vs baseline: 1.2035x; 1.0157x over previous
//
#include <hip/hip_runtime.h>

#define SEQ 4096
#define DIM 1280
#define NH 16
#define HD 80
#define HQ 96
#define TDIM 3840

// softmax scale (1/sqrt(80)) * log2(e), folded into Q at repack
#define QSC 0.16129842980505168f

typedef __bf16 bf16x8 __attribute__((ext_vector_type(8)));
typedef __bf16 bf16x4 __attribute__((ext_vector_type(4)));
typedef float f32x4 __attribute__((ext_vector_type(4)));

__device__ __forceinline__ unsigned short f2bf(float f) {
  unsigned int u = __builtin_bit_cast(unsigned int, f);
  u += 0x7FFF + ((u >> 16) & 1);
  return (unsigned short)(u >> 16);
}
__device__ __forceinline__ float bf2f(unsigned short b) {
  unsigned int u = ((unsigned int)b) << 16;
  return __builtin_bit_cast(float, u);
}
__device__ __forceinline__ unsigned int cvtpk(float a, float b) {
  unsigned int r;
  asm("v_cvt_pk_bf16_f32 %0, %1, %2" : "=v"(r) : "v"(a), "v"(b));
  return r;
}

__device__ __forceinline__ void gload_lds16(const void* g, void* l) {
  __builtin_amdgcn_global_load_lds(
      (const __attribute__((address_space(1))) unsigned int*)g,
      (__attribute__((address_space(3))) unsigned int*)l, 16, 0, 0);
}

// ---------------- fused prep: fp32->bf16 x3 + cos/sin table ----------------
__global__ __launch_bounds__(256) void prep(const float* __restrict__ X,
                                            const float* __restrict__ Wq,
                                            const float* __restrict__ Wp,
                                            const float* __restrict__ rope,
                                            unsigned short* __restrict__ Xb,
                                            unsigned short* __restrict__ Wqb,
                                            unsigned short* __restrict__ Wpb,
                                            float* __restrict__ ct, float* __restrict__ st) {
  constexpr int N0 = SEQ * DIM / 4;
  constexpr int N1 = TDIM * DIM / 4;
  constexpr int N2 = DIM * DIM / 4;
  constexpr int N3 = SEQ * HD / 4;
  const int stride = gridDim.x * 256;
  for (int i = blockIdx.x * 256 + threadIdx.x; i < N0 + N1 + N2 + N3; i += stride) {
    if (i < N0 + N1 + N2) {
      const float4* src;
      unsigned short* dst;
      int j;
      if (i < N0) {
        src = (const float4*)X; dst = Xb; j = i;
      } else if (i < N0 + N1) {
        src = (const float4*)Wq; dst = Wqb; j = i - N0;
      } else {
        src = (const float4*)Wp; dst = Wpb; j = i - N0 - N1;
      }
      float4 f = src[j];
      ushort4 o;
      o.x = f2bf(f.x); o.y = f2bf(f.y); o.z = f2bf(f.z); o.w = f2bf(f.w);
      ((ushort4*)dst)[j] = o;
    } else {
      const int j = i - N0 - N1 - N2;
      float4 v = ((const float4*)rope)[j];
      float4 c, s;
      c.x = cosf(v.x); c.y = cosf(v.y); c.z = cosf(v.z); c.w = cosf(v.w);
      s.x = sinf(v.x); s.y = sinf(v.y); s.z = sinf(v.z); s.w = sinf(v.w);
      ((float4*)ct)[j] = c;
      ((float4*)st)[j] = s;
    }
  }
}

// ---------------- QKV GEMM: 256x256 tile, BK=64, 4-phase interleave ----------------
__global__ __launch_bounds__(512, 1) void gemmq(const unsigned short* __restrict__ A,
                                                const unsigned short* __restrict__ B,
                                                const float* __restrict__ bias,
                                                unsigned short* __restrict__ Cout) {
  __shared__ char smem[131072];
  const int tid = threadIdx.x;
  const int l = tid & 63, w = tid >> 6;
  const int row16 = l & 15, kg = l >> 4;
  const int wr = w >> 2, wc = w & 3;

  const int bid = blockIdx.x;
  const int swz = (bid & 7) * 30 + (bid >> 3);
  const int ny = swz / 15, nx = swz - ny * 15;
  const int brow = ny * 256, bcol = nx * 256;

  constexpr int Kb = 2560;
  const char* Ag = (const char*)A + (size_t)brow * Kb;
  const char* Bg = (const char*)B + (size_t)bcol * Kb;

  unsigned soff[4], sdst[4];
#pragma unroll
  for (int i = 0; i < 4; ++i) {
    const int u = ((w * 4 + i) << 6) + l;
    const int row = u >> 3;
    const int cg = (u & 7) ^ (row & 7);
    soff[i] = row * Kb + cg * 16;
    sdst[i] = u * 16;
  }
  auto SGA = [&](int kt, int b, int i) {
    gload_lds16(Ag + kt * 128 + soff[i], smem + b * 65536 + sdst[i]);
  };
  auto SGB = [&](int kt, int b, int i) {
    gload_lds16(Bg + kt * 128 + soff[i], smem + b * 65536 + 32768 + sdst[i]);
  };

  f32x4 acc[8][4] = {};
  const int arow = (wr * 128 + row16) * 128;
  const int brow_ = (wc * 64 + row16) * 128;
  int cswz[2];
#pragma unroll
  for (int ks = 0; ks < 2; ++ks) cswz[ks] = (ks * 64 + kg * 16) ^ ((row16 & 7) << 4);

#pragma unroll
  for (int i = 0; i < 4; ++i) SGA(0, 0, i);
#pragma unroll
  for (int i = 0; i < 4; ++i) SGB(0, 0, i);

  constexpr int NKT = 20;
#pragma unroll 1
  for (int t = 0; t < NKT; ++t) {
    const int cb = t & 1, nb2 = cb ^ 1;
    const bool more = (t + 1 < NKT);
    if (more) {
      SGA(t + 1, nb2, 0);
      SGB(t + 1, nb2, 0);
      asm volatile("s_waitcnt vmcnt(2)" ::: "memory");
    } else {
      asm volatile("s_waitcnt vmcnt(0)" ::: "memory");
    }
    __builtin_amdgcn_s_barrier();
    __builtin_amdgcn_sched_barrier(0);
    const char* Ab = smem + cb * 65536;
    const char* Bb = Ab + 32768;

    bf16x8 bf0[4], af[4];
#pragma unroll
    for (int ni = 0; ni < 4; ++ni) bf0[ni] = *(const bf16x8*)(Bb + brow_ + ni * 2048 + cswz[0]);
#pragma unroll
    for (int m4 = 0; m4 < 4; ++m4) af[m4] = *(const bf16x8*)(Ab + arow + m4 * 2048 + cswz[0]);
    asm volatile("s_waitcnt lgkmcnt(0)" ::: "memory");
    __builtin_amdgcn_sched_barrier(0);
    __builtin_amdgcn_s_setprio(1);
#pragma unroll
    for (int m4 = 0; m4 < 4; ++m4)
#pragma unroll
      for (int ni = 0; ni < 4; ++ni)
        acc[m4][ni] = __builtin_amdgcn_mfma_f32_16x16x32_bf16(af[m4], bf0[ni], acc[m4][ni], 0, 0, 0);
    __builtin_amdgcn_s_setprio(0);
    __builtin_amdgcn_s_barrier();
    if (more) { SGA(t + 1, nb2, 1); SGB(t + 1, nb2, 1); }
#pragma unroll
    for (int m4 = 0; m4 < 4; ++m4) af[m4] = *(const bf16x8*)(Ab + arow + (m4 + 4) * 2048 + cswz[0]);
    asm volatile("s_waitcnt lgkmcnt(0)" ::: "memory");
    __builtin_amdgcn_sched_barrier(0);
    __builtin_amdgcn_s_setprio(1);
#pragma unroll
    for (int m4 = 0; m4 < 4; ++m4)
#pragma unroll
      for (int ni = 0; ni < 4; ++ni)
        acc[m4 + 4][ni] =
            __builtin_amdgcn_mfma_f32_16x16x32_bf16(af[m4], bf0[ni], acc[m4 + 4][ni], 0, 0, 0);
    __builtin_amdgcn_s_setprio(0);
    __builtin_amdgcn_s_barrier();
    if (more) { SGA(t + 1, nb2, 2); SGB(t + 1, nb2, 2); }
#pragma unroll
    for (int ni = 0; ni < 4; ++ni) bf0[ni] = *(const bf16x8*)(Bb + brow_ + ni * 2048 + cswz[1]);
#pragma unroll
    for (int m4 = 0; m4 < 4; ++m4) af[m4] = *(const bf16x8*)(Ab + arow + m4 * 2048 + cswz[1]);
    asm volatile("s_waitcnt lgkmcnt(0)" ::: "memory");
    __builtin_amdgcn_sched_barrier(0);
    __builtin_amdgcn_s_setprio(1);
#pragma unroll
    for (int m4 = 0; m4 < 4; ++m4)
#pragma unroll
      for (int ni = 0; ni < 4; ++ni)
        acc[m4][ni] = __builtin_amdgcn_mfma_f32_16x16x32_bf16(af[m4], bf0[ni], acc[m4][ni], 0, 0, 0);
    __builtin_amdgcn_s_setprio(0);
    __builtin_amdgcn_s_barrier();
    if (more) { SGA(t + 1, nb2, 3); SGB(t + 1, nb2, 3); }
#pragma unroll
    for (int m4 = 0; m4 < 4; ++m4) af[m4] = *(const bf16x8*)(Ab + arow + (m4 + 4) * 2048 + cswz[1]);
    asm volatile("s_waitcnt lgkmcnt(0)" ::: "memory");
    __builtin_amdgcn_sched_barrier(0);
    __builtin_amdgcn_s_setprio(1);
#pragma unroll
    for (int m4 = 0; m4 < 4; ++m4)
#pragma unroll
      for (int ni = 0; ni < 4; ++ni)
        acc[m4 + 4][ni] =
            __builtin_amdgcn_mfma_f32_16x16x32_bf16(af[m4], bf0[ni], acc[m4 + 4][ni], 0, 0, 0);
    __builtin_amdgcn_s_setprio(0);
    __builtin_amdgcn_s_barrier();
  }

#pragma unroll
  for (int ni = 0; ni < 4; ++ni) {
    const int col = bcol + wc * 64 + ni * 16 + row16;
    const float bv = bias[col];
#pragma unroll
    for (int mi = 0; mi < 8; ++mi) {
      const int row = brow + wr * 128 + mi * 16 + kg * 4;
#pragma unroll
      for (int r = 0; r < 4; ++r)
        Cout[(size_t)(row + r) * TDIM + col] = f2bf(acc[mi][ni][r] + bv);
    }
  }
}

// ---------------- out-proj GEMM: 128x256 tile, BK=64, 2-phase, fp32 out ----------------
__global__ __launch_bounds__(512, 1) void gemmp(const unsigned short* __restrict__ A,
                                                const unsigned short* __restrict__ B,
                                                const float* __restrict__ bias,
                                                float* __restrict__ Cout) {
  __shared__ char smem[98304];  // A: 2 x 16KB at 0; B: 2 x 32KB at 32768
  const int tid = threadIdx.x;
  const int l = tid & 63, w = tid >> 6;
  const int row16 = l & 15, kg = l >> 4;
  const int wr = w >> 2, wc = w & 3;

  const int bid = blockIdx.x;
  const int swz = (bid & 7) * 20 + (bid >> 3);
  const int ny = swz / 5, nx = swz - ny * 5;
  const int brow = ny * 128, bcol = nx * 256;

  constexpr int Kb = 2560;
  const char* Ag = (const char*)A + (size_t)brow * Kb;
  const char* Bg = (const char*)B + (size_t)bcol * Kb;

  unsigned soff[6], sdst[6];
#pragma unroll
  for (int jj = 0; jj < 6; ++jj) {
    const int u = tid + 512 * jj;
    const int v = (u < 1024) ? u : (u - 1024);
    const int row = v >> 3;
    const int cg = (v & 7) ^ (row & 7);
    soff[jj] = row * Kb + cg * 16;
    sdst[jj] = v * 16;
  }
  auto SG = [&](int kt, int b, int part) {
#pragma unroll
    for (int jj3 = 0; jj3 < 3; ++jj3) {
      const int jj = part * 3 + jj3;
      const bool isa = (jj < 2);
      gload_lds16((isa ? Ag : Bg) + kt * 128 + soff[jj],
                  smem + (isa ? b * 16384 : 32768 + b * 32768) + sdst[jj]);
    }
  };

  f32x4 acc[4][4] = {};
  const int arow = (wr * 64 + row16) * 128;
  const int brow_ = (wc * 64 + row16) * 128;
  int cswz[2];
#pragma unroll
  for (int ks = 0; ks < 2; ++ks) cswz[ks] = (ks * 64 + kg * 16) ^ ((row16 & 7) << 4);

  SG(0, 0, 0);
  SG(0, 0, 1);

  constexpr int NKT = 20;
#pragma unroll 1
  for (int t = 0; t < NKT; ++t) {
    const int cb = t & 1, nb2 = cb ^ 1;
    const bool more = (t + 1 < NKT);
    if (more) {
      SG(t + 1, nb2, 0);
      asm volatile("s_waitcnt vmcnt(3)" ::: "memory");
    } else {
      asm volatile("s_waitcnt vmcnt(0)" ::: "memory");
    }
    __builtin_amdgcn_s_barrier();
    __builtin_amdgcn_sched_barrier(0);
    const char* Ab = smem + cb * 16384;
    const char* Bb = smem + 32768 + cb * 32768;

    bf16x8 bf0[4], af[4];
#pragma unroll
    for (int ni = 0; ni < 4; ++ni) bf0[ni] = *(const bf16x8*)(Bb + brow_ + ni * 2048 + cswz[0]);
#pragma unroll
    for (int mi = 0; mi < 4; ++mi) af[mi] = *(const bf16x8*)(Ab + arow + mi * 2048 + cswz[0]);
    asm volatile("s_waitcnt lgkmcnt(0)" ::: "memory");
    __builtin_amdgcn_sched_barrier(0);
    __builtin_amdgcn_s_setprio(1);
#pragma unroll
    for (int mi = 0; mi < 4; ++mi)
#pragma unroll
      for (int ni = 0; ni < 4; ++ni)
        acc[mi][ni] = __builtin_amdgcn_mfma_f32_16x16x32_bf16(af[mi], bf0[ni], acc[mi][ni], 0, 0, 0);
    __builtin_amdgcn_s_setprio(0);
    __builtin_amdgcn_s_barrier();
    if (more) SG(t + 1, nb2, 1);
#pragma unroll
    for (int ni = 0; ni < 4; ++ni) bf0[ni] = *(const bf16x8*)(Bb + brow_ + ni * 2048 + cswz[1]);
#pragma unroll
    for (int mi = 0; mi < 4; ++mi) af[mi] = *(const bf16x8*)(Ab + arow + mi * 2048 + cswz[1]);
    asm volatile("s_waitcnt lgkmcnt(0)" ::: "memory");
    __builtin_amdgcn_sched_barrier(0);
    __builtin_amdgcn_s_setprio(1);
#pragma unroll
    for (int mi = 0; mi < 4; ++mi)
#pragma unroll
      for (int ni = 0; ni < 4; ++ni)
        acc[mi][ni] = __builtin_amdgcn_mfma_f32_16x16x32_bf16(af[mi], bf0[ni], acc[mi][ni], 0, 0, 0);
    __builtin_amdgcn_s_setprio(0);
    __builtin_amdgcn_s_barrier();
  }

#pragma unroll
  for (int ni = 0; ni < 4; ++ni) {
    const int col = bcol + wc * 64 + ni * 16 + row16;
    const float bv = bias[col];
#pragma unroll
    for (int mi = 0; mi < 4; ++mi) {
      const int row = brow + wr * 64 + mi * 16 + kg * 4;
#pragma unroll
      for (int r = 0; r < 4; ++r)
        Cout[(size_t)(row + r) * DIM + col] = acc[mi][ni][r] + bv;
    }
  }
}

// ---------------- fused RoPE-repack (vectorized) + V transpose ----------------
// Layouts IDENTICAL to R12: Qr,Kr [h][s][96] (zero-padded 80..95), Vp permuted image.
// bid < SEQ: rope for s=bid. bid >= SEQ: V transpose tile.
__global__ __launch_bounds__(256) void rope_vt(const unsigned short* __restrict__ Y,
                                               const float* __restrict__ ct,
                                               const float* __restrict__ st,
                                               unsigned short* __restrict__ Qr,
                                               unsigned short* __restrict__ Kr,
                                               unsigned short* __restrict__ Vp) {
  __shared__ unsigned short tile[64][128];
  const int bid = blockIdx.x, tid = threadIdx.x;
  if (bid < SEQ) {
    const int s = bid;
    if (tid < 160) {
      const int h = tid / 10, j4 = (tid - h * 10) * 4;
      const unsigned short* yq = Y + (size_t)s * TDIM + h * HD;
      const unsigned short* yk = yq + DIM;
      const float4 c0 = *(const float4*)&ct[s * HD + j4];
      const float4 c1 = *(const float4*)&ct[s * HD + j4 + 40];
      const float4 s0 = *(const float4*)&st[s * HD + j4];
      const float4 s1 = *(const float4*)&st[s * HD + j4 + 40];
      const ushort4 q0 = *(const ushort4*)(yq + j4);
      const ushort4 q1 = *(const ushort4*)(yq + j4 + 40);
      const ushort4 k0 = *(const ushort4*)(yk + j4);
      const ushort4 k1 = *(const ushort4*)(yk + j4 + 40);
      ushort4 oq0, oq1, ok0, ok1;
      oq0.x = f2bf((bf2f(q0.x) * c0.x - bf2f(q1.x) * s0.x) * QSC);
      oq0.y = f2bf((bf2f(q0.y) * c0.y - bf2f(q1.y) * s0.y) * QSC);
      oq0.z = f2bf((bf2f(q0.z) * c0.z - bf2f(q1.z) * s0.z) * QSC);
      oq0.w = f2bf((bf2f(q0.w) * c0.w - bf2f(q1.w) * s0.w) * QSC);
      oq1.x = f2bf((bf2f(q1.x) * c1.x + bf2f(q0.x) * s1.x) * QSC);
      oq1.y = f2bf((bf2f(q1.y) * c1.y + bf2f(q0.y) * s1.y) * QSC);
      oq1.z = f2bf((bf2f(q1.z) * c1.z + bf2f(q0.z) * s1.z) * QSC);
      oq1.w = f2bf((bf2f(q1.w) * c1.w + bf2f(q0.w) * s1.w) * QSC);
      ok0.x = f2bf(bf2f(k0.x) * c0.x - bf2f(k1.x) * s0.x);
      ok0.y = f2bf(bf2f(k0.y) * c0.y - bf2f(k1.y) * s0.y);
      ok0.z = f2bf(bf2f(k0.z) * c0.z - bf2f(k1.z) * s0.z);
      ok0.w = f2bf(bf2f(k0.w) * c0.w - bf2f(k1.w) * s0.w);
      ok1.x = f2bf(bf2f(k1.x) * c1.x + bf2f(k0.x) * s1.x);
      ok1.y = f2bf(bf2f(k1.y) * c1.y + bf2f(k0.y) * s1.y);
      ok1.z = f2bf(bf2f(k1.z) * c1.z + bf2f(k0.z) * s1.z);
      ok1.w = f2bf(bf2f(k1.w) * c1.w + bf2f(k0.w) * s1.w);
      const size_t o = ((size_t)h * SEQ + s) * HQ;
      *(ushort4*)&Qr[o + j4] = oq0;
      *(ushort4*)&Qr[o + j4 + 40] = oq1;
      *(ushort4*)&Kr[o + j4] = ok0;
      *(ushort4*)&Kr[o + j4 + 40] = ok1;
    } else if (tid < 224) {
      const int u = tid - 160;
      const int h = u >> 2, g = u & 3;
      const size_t o = ((size_t)h * SEQ + s) * HQ + 80 + g * 4;
      ushort4 z = {0, 0, 0, 0};
      *(ushort4*)&Qr[o] = z;
      *(ushort4*)&Kr[o] = z;
    }
  } else {
    const int b = bid - SEQ;
    const int h = b >> 6, s0 = (b & 63) * 64;
    const unsigned short* src = Y + 2 * DIM + h * HD;
    for (int u = tid; u < 640; u += 256) {
      const int s = u / 10, j = u - s * 10;
      uint4 v = *(const uint4*)(src + (size_t)(s0 + s) * TDIM + j * 8);
      *(uint4*)&tile[s][(j ^ ((s >> 3) & 7)) << 3] = v;
    }
    __syncthreads();
    for (int u = tid; u < 640; u += 256) {
      const int d = u >> 3, g = u & 7;
      const int gl = g ^ (d & 7);
      const int base_s = (gl & 1) * 32 + (gl >> 1) * 4;
      unsigned short tmp[8];
#pragma unroll
      for (int sub = 0; sub < 8; ++sub) {
        const int s = base_s + (sub >> 2) * 16 + (sub & 3);
        tmp[sub] = tile[s][(((d >> 3) ^ ((s >> 3) & 7)) << 3) + (d & 7)];
      }
      *(uint4*)(Vp + (size_t)(h * HD + d) * SEQ + s0 + g * 8) = *(uint4*)tmp;
    }
  }
}

// ---------------- Flash attention v8: ring-3 counted vmcnt + 1-deep PV pipeline ----
// (bit-identical to the R12-passing attn8)
__global__ __launch_bounds__(256, 2) void attn8(const unsigned short* __restrict__ Qr,
                                                const unsigned short* __restrict__ Kr,
                                                const unsigned short* __restrict__ Vp,
                                                unsigned short* __restrict__ Ob) {
  constexpr int KBYT = 12288;
  constexpr int VBYT = 10240;
  constexpr int BUFB = KBYT + VBYT;  // 22528
  constexpr int NT = SEQ / 64;       // 64 tiles
  __shared__ char smem[3 * BUFB];

  const int tid = threadIdx.x;
  const int l = tid & 63, w = tid >> 6;
  const int row16 = l & 15, kg = l >> 4;
  const int bid = blockIdx.x;
  const int h = bid & 15;
  const int q0 = (bid >> 4) * 128 + w * 32;
  const size_t hs = (size_t)h * SEQ;
  const bool loww = (w < 2);

  const unsigned short* Qh = Qr + hs * HQ;
  const char* Kh = (const char*)(Kr + hs * HQ);
  const char* Vh = (const char*)(Vp + (size_t)h * HD * SEQ);

  // staging: 1408 16B-units (768 K + 640 V); unit u = tid + 256*i
  unsigned soff[6], sdst[6];
  bool isk[6];
  const int cnt = (tid < 128) ? 6 : 5;
#pragma unroll
  for (int i = 0; i < 6; ++i) {
    const int u = tid + 256 * i;
    if (u < 768) {
      soff[i] = (u & 63) * 192 + (u >> 6) * 16;
      isk[i] = true;
    } else {
      const int v = u - 768;
      soff[i] = (v >> 3) * 8192 + (v & 7) * 16;
      isk[i] = false;
    }
    sdst[i] = u << 4;
  }
  auto STAGE = [&](int t, int bb) {
    const char* kb = Kh + (size_t)t * 12288;
    const char* vb = Vh + (size_t)t * 128;
#pragma unroll
    for (int i = 0; i < 6; ++i)
      if (i < cnt) gload_lds16((isk[i] ? kb : vb) + soff[i], smem + bb + sdst[i]);
  };

  // LDS read bases (tile-invariant)
  const int kbase = row16 * 16;  // + (4c+kg)*1024 + nb*256
  int vb_[2];
#pragma unroll
  for (int ks = 0; ks < 2; ++ks)
    vb_[ks] = KBYT + row16 * 128 + ((((kg << 1) | ks) ^ (row16 & 7)) << 4);  // + n5*2048

  // Q fragments (B-operand of swapped QK^T): q = q0 + qb*16 + row16
  bf16x8 qf[2][3];
#pragma unroll
  for (int qb = 0; qb < 2; ++qb)
#pragma unroll
    for (int c = 0; c < 3; ++c)
      qf[qb][c] = *(const bf16x8*)&Qh[(size_t)(q0 + qb * 16 + row16) * HQ + c * 32 + kg * 8];
  // Force the compiler's vmcnt wait for qf HERE (pre-pipeline), not inside the loop.
  asm volatile("" ::"v"(qf[0][0]), "v"(qf[0][1]), "v"(qf[0][2]));
  asm volatile("" ::"v"(qf[1][0]), "v"(qf[1][1]), "v"(qf[1][2]));

  union { bf16x8 v; unsigned int u[4]; } ones;
  ones.u[0] = ones.u[1] = ones.u[2] = ones.u[3] = 0x3F803F80u;

  float m_run[2] = {-3.0e38f, -3.0e38f};
  f32x4 oacc[2][6] = {};  // [qb][d-block 0..4, 5 = row-sum l]

  // pipeline state: packed P and V fragments of the previous tile (A/B sets)
  unsigned pfA[2][2][4], pfB[2][2][4];
  bf16x8 vfA[5][2], vfB[5][2];

  // PV of a previous tile: pure register MFMA (no LDS) -> can overlap SM of cur tile
  auto PV = [&](const unsigned (&pfi)[2][2][4], const bf16x8 (&vfi)[5][2]) {
    __builtin_amdgcn_s_setprio(1);
#pragma unroll
    for (int qb = 0; qb < 2; ++qb)
#pragma unroll
      for (int ks = 0; ks < 2; ++ks) {
        union { bf16x8 v; unsigned int u[4]; } pf;
        pf.u[0] = pfi[qb][ks][0];
        pf.u[1] = pfi[qb][ks][1];
        pf.u[2] = pfi[qb][ks][2];
        pf.u[3] = pfi[qb][ks][3];
#pragma unroll
        for (int n5 = 0; n5 < 5; ++n5)
          oacc[qb][n5] =
              __builtin_amdgcn_mfma_f32_16x16x32_bf16(vfi[n5][ks], pf.v, oacc[qb][n5], 0, 0, 0);
        oacc[qb][5] = __builtin_amdgcn_mfma_f32_16x16x32_bf16(ones.v, pf.v, oacc[qb][5], 0, 0, 0);
      }
    __builtin_amdgcn_s_setprio(0);
  };

  // One pipeline step: QK(t) -> SM(t) -> pack into pfo; V(t) -> vfo; PV(t-1) from pfi/vfi.
  auto STEP = [&](const char* B, unsigned (&pfo)[2][2][4], bf16x8 (&vfo)[5][2],
                  const unsigned (&pfi)[2][2][4], const bf16x8 (&vfi)[5][2], bool dopv) {
    // ---- QK^T: per d-chunk c, load 4 K-frags then 8 MFMAs ----
    f32x4 sacc[2][4] = {};
#pragma unroll
    for (int c = 0; c < 3; ++c) {
      bf16x8 kf[4];
      const char* kc = B + (4 * c + kg) * 1024 + kbase;
#pragma unroll
      for (int nb = 0; nb < 4; ++nb) kf[nb] = *(const bf16x8*)(kc + nb * 256);
      __builtin_amdgcn_s_setprio(1);
#pragma unroll
      for (int qb = 0; qb < 2; ++qb)
#pragma unroll
        for (int nb = 0; nb < 4; ++nb)
          sacc[qb][nb] =
              __builtin_amdgcn_mfma_f32_16x16x32_bf16(kf[nb], qf[qb][c], sacc[qb][nb], 0, 0, 0);
      __builtin_amdgcn_s_setprio(0);
    }
    // ---- V fragments of tile t -> registers (held until next region) ----
#pragma unroll
    for (int n5 = 0; n5 < 5; ++n5)
#pragma unroll
      for (int ks = 0; ks < 2; ++ks) vfo[n5][ks] = *(const bf16x8*)(B + vb_[ks] + n5 * 2048);
    // ---- PV of previous tile (independent of SM below -> co-issues with it) ----
    if (dopv) PV(pfi, vfi);
    // ---- softmax: per-lane local max; cross-lane ONLY when threshold exceeded ----
    float pl[2];
#pragma unroll
    for (int qb = 0; qb < 2; ++qb) {
      float a0 = fmaxf(fmaxf(sacc[qb][0][0], sacc[qb][0][1]), fmaxf(sacc[qb][0][2], sacc[qb][0][3]));
      float a1 = fmaxf(fmaxf(sacc[qb][1][0], sacc[qb][1][1]), fmaxf(sacc[qb][1][2], sacc[qb][1][3]));
      float a2 = fmaxf(fmaxf(sacc[qb][2][0], sacc[qb][2][1]), fmaxf(sacc[qb][2][2], sacc[qb][2][3]));
      float a3 = fmaxf(fmaxf(sacc[qb][3][0], sacc[qb][3][1]), fmaxf(sacc[qb][3][2], sacc[qb][3][3]));
      pl[qb] = fmaxf(fmaxf(a0, a1), fmaxf(a2, a3));
    }
    // fast path: no lane's local max grew past m_run + 8 -> keep m_run, P <= 2^8
    if (!__all((pl[0] - m_run[0] <= 8.0f) & (pl[1] - m_run[1] <= 8.0f))) {
#pragma unroll
      for (int qb = 0; qb < 2; ++qb) {
        float m0 = pl[qb];
        m0 = fmaxf(m0, __shfl_xor(m0, 16, 64));
        m0 = fmaxf(m0, __shfl_xor(m0, 32, 64));
        const float mn = fmaxf(m_run[qb], m0);
        const float fac = __builtin_amdgcn_exp2f(m_run[qb] - mn);
        m_run[qb] = mn;
        // RAW dep on oacc orders this after PV(t-1) above -- correct rescale point
#pragma unroll
        for (int n6 = 0; n6 < 6; ++n6)
#pragma unroll
          for (int r = 0; r < 4; ++r) oacc[qb][n6][r] *= fac;
      }
    }
#pragma unroll
    for (int qb = 0; qb < 2; ++qb)
#pragma unroll
      for (int nb = 0; nb < 4; ++nb)
#pragma unroll
        for (int r = 0; r < 4; ++r)
          sacc[qb][nb][r] = __builtin_amdgcn_exp2f(sacc[qb][nb][r] - m_run[qb]);
    // ---- pack P -> bf16 fragments (k-map matches Vp image) ----
#pragma unroll
    for (int qb = 0; qb < 2; ++qb)
#pragma unroll
      for (int ks = 0; ks < 2; ++ks) {
        pfo[qb][ks][0] = cvtpk(sacc[qb][2 * ks][0], sacc[qb][2 * ks][1]);
        pfo[qb][ks][1] = cvtpk(sacc[qb][2 * ks][2], sacc[qb][2 * ks][3]);
        pfo[qb][ks][2] = cvtpk(sacc[qb][2 * ks + 1][0], sacc[qb][2 * ks + 1][1]);
        pfo[qb][ks][3] = cvtpk(sacc[qb][2 * ks + 1][2], sacc[qb][2 * ks + 1][3]);
      }
  };

  // ---- prologue: fill stages for tiles 0 and 1 ----
  STAGE(0, 0);
  STAGE(1, BUFB);

  // iter 0 (even -> set A), no PV
  STAGE(2, 2 * BUFB);
  if (loww)
    asm volatile("s_waitcnt vmcnt(12)" ::: "memory");
  else
    asm volatile("s_waitcnt vmcnt(10)" ::: "memory");
  __builtin_amdgcn_s_barrier();
  __builtin_amdgcn_sched_barrier(0);
  STEP(smem + 0, pfA, vfA, pfB, vfB, false);
  asm volatile("" ::: "memory");
  __builtin_amdgcn_s_barrier();

  int cur = 1;  // buffer index of the tile being computed
  // iters 1..60 as 30 unrolled pairs (odd -> B, even -> A)
#pragma unroll 1
  for (int tp = 1; tp <= 59; tp += 2) {
    // iter tp (odd): FRONT B, PV from A
    int sb = (cur == 0) ? 2 : (cur - 1);
    STAGE(tp + 2, sb * BUFB);
    if (loww)
      asm volatile("s_waitcnt vmcnt(12)" ::: "memory");
    else
      asm volatile("s_waitcnt vmcnt(10)" ::: "memory");
    __builtin_amdgcn_s_barrier();
    __builtin_amdgcn_sched_barrier(0);
    STEP(smem + cur * BUFB, pfB, vfB, pfA, vfA, true);
    asm volatile("" ::: "memory");
    __builtin_amdgcn_s_barrier();
    cur = (cur == 2) ? 0 : (cur + 1);
    // iter tp+1 (even): FRONT A, PV from B
    sb = (cur == 0) ? 2 : (cur - 1);
    STAGE(tp + 3, sb * BUFB);
    if (loww)
      asm volatile("s_waitcnt vmcnt(12)" ::: "memory");
    else
      asm volatile("s_waitcnt vmcnt(10)" ::: "memory");
    __builtin_amdgcn_s_barrier();
    __builtin_amdgcn_sched_barrier(0);
    STEP(smem + cur * BUFB, pfA, vfA, pfB, vfB, true);
    asm volatile("" ::: "memory");
    __builtin_amdgcn_s_barrier();
    cur = (cur == 2) ? 0 : (cur + 1);
  }
  // iter 61 (odd): stage tile 63, FRONT B, PV from A
  {
    int sb = (cur == 0) ? 2 : (cur - 1);
    STAGE(63, sb * BUFB);
    if (loww)
      asm volatile("s_waitcnt vmcnt(12)" ::: "memory");
    else
      asm volatile("s_waitcnt vmcnt(10)" ::: "memory");
    __builtin_amdgcn_s_barrier();
    __builtin_amdgcn_sched_barrier(0);
    STEP(smem + cur * BUFB, pfB, vfB, pfA, vfA, true);
    asm volatile("" ::: "memory");
    __builtin_amdgcn_s_barrier();
    cur = (cur == 2) ? 0 : (cur + 1);
  }
  // iter 62 (even): one stage (63) still in flight
  if (loww)
    asm volatile("s_waitcnt vmcnt(6)" ::: "memory");
  else
    asm volatile("s_waitcnt vmcnt(5)" ::: "memory");
  __builtin_amdgcn_s_barrier();
  __builtin_amdgcn_sched_barrier(0);
  STEP(smem + cur * BUFB, pfA, vfA, pfB, vfB, true);
  asm volatile("" ::: "memory");
  __builtin_amdgcn_s_barrier();
  cur = (cur == 2) ? 0 : (cur + 1);
  // iter 63 (odd): drain fully
  asm volatile("s_waitcnt vmcnt(0)" ::: "memory");
  __builtin_amdgcn_s_barrier();
  __builtin_amdgcn_sched_barrier(0);
  STEP(smem + cur * BUFB, pfB, vfB, pfA, vfA, true);
  // final PV of tile 63
  PV(pfB, vfB);

  // ---- epilogue: d = n5*16 + kg*4 + r, q = q0 + qb*16 + row16 ----
#pragma unroll
  for (int qb = 0; qb < 2; ++qb) {
    const float rl = 1.0f / oacc[qb][5][0];
    unsigned short* orow = Ob + (size_t)(q0 + qb * 16 + row16) * DIM + h * HD + kg * 4;
#pragma unroll
    for (int n5 = 0; n5 < 5; ++n5) {
      ushort4 o;
      o.x = f2bf(oacc[qb][n5][0] * rl);
      o.y = f2bf(oacc[qb][n5][1] * rl);
      o.z = f2bf(oacc[qb][n5][2] * rl);
      o.w = f2bf(oacc[qb][n5][3] * rl);
      *(ushort4*)(orow + n5 * 16) = o;
    }
  }
}

// ---------------- host ----------------
extern "C" void kernel_launch(void* const* d_in, const int* in_sizes, int n_in, void* d_out,
                              int out_size, void* d_ws, size_t ws_size, hipStream_t stream) {
  (void)in_sizes; (void)n_in; (void)out_size; (void)ws_size;
  const float* hidden = (const float*)d_in[0];
  const float* rope = (const float*)d_in[2];
  const float* qkv_w = (const float*)d_in[3];
  const float* qkv_b = (const float*)d_in[4];
  const float* proj_w = (const float*)d_in[5];
  const float* proj_b = (const float*)d_in[6];

  char* p = (char*)d_ws;
  unsigned short* Xb = (unsigned short*)p;       p += (size_t)SEQ * DIM * 2;
  unsigned short* Wq = (unsigned short*)p;       p += (size_t)TDIM * DIM * 2;
  unsigned short* Wp = (unsigned short*)p;       p += (size_t)DIM * DIM * 2;
  float* ct = (float*)p;                         p += (size_t)SEQ * HD * 4;
  float* st = (float*)p;                         p += (size_t)SEQ * HD * 4;
  unsigned short* Y = (unsigned short*)p;        p += (size_t)SEQ * TDIM * 2;
  unsigned short* Qr = (unsigned short*)p;       p += (size_t)NH * SEQ * HQ * 2;
  unsigned short* Kr = (unsigned short*)p;       p += (size_t)NH * SEQ * HQ * 2;
  unsigned short* Vp = (unsigned short*)p;       p += (size_t)NH * HD * SEQ * 2;
  unsigned short* Ob = (unsigned short*)p;       p += (size_t)SEQ * DIM * 2;

  prep<<<2048, 256, 0, stream>>>(hidden, qkv_w, proj_w, rope, Xb, Wq, Wp, ct, st);
  gemmq<<<240, 512, 0, stream>>>(Xb, Wq, qkv_b, Y);
  rope_vt<<<SEQ + NH * (SEQ / 64), 256, 0, stream>>>(Y, ct, st, Qr, Kr, Vp);
  attn8<<<512, 256, 0, stream>>>(Qr, Kr, Vp, Ob);
  gemmp<<<160, 512, 0, stream>>>(Ob, Wp, proj_b, (float*)d_out);
}